// Round 1
// baseline (3671.964 us; speedup 1.0000x reference)
//
#include <hip/hip_runtime.h>
#include <math.h>

#define BATCH 256
#define NH 512
#define NCOND 1024
#define NV 32002
#define NT 15
#define NVT 501   // ceil(NV/64)

// ---------------- seed token -> preds col 0 ----------------
__global__ void k_seed(const int* __restrict__ cap, int* __restrict__ preds){
  int b = threadIdx.x;
  preds[b*NT + 0] = cap[b];
}

// ---------------- h0 = img @ W_cond^T + b_cond ----------------
// grid (NH/64, BATCH/64), 256 thr. 64x64 tile, K=1024, Kt=32.
__global__ __launch_bounds__(256) void k_h0(const float* __restrict__ img,
                                            const float* __restrict__ Wc,
                                            const float* __restrict__ bc,
                                            float* __restrict__ h0){
  __shared__ float As[64*36];
  __shared__ float Bs[64*36];
  int tid = threadIdx.x;
  int tx = tid & 15, ty = tid >> 4;
  int jbase = blockIdx.x * 64;
  int bbase = blockIdx.y * 64;
  int lrow = tid >> 3;
  int lc4  = (tid & 7) << 2;
  float acc[4][4] = {};
  for (int k0 = 0; k0 < NCOND; k0 += 32){
    #pragma unroll
    for (int rr = 0; rr < 64; rr += 32){
      *(float4*)&As[(lrow+rr)*36 + lc4] =
          *(const float4*)(img + (size_t)(bbase+lrow+rr)*NCOND + k0 + lc4);
      *(float4*)&Bs[(lrow+rr)*36 + lc4] =
          *(const float4*)(Wc + (size_t)(jbase+lrow+rr)*NCOND + k0 + lc4);
    }
    __syncthreads();
    #pragma unroll
    for (int kk = 0; kk < 32; kk += 4){
      float4 a[4], w[4];
      #pragma unroll
      for (int i=0;i<4;i++) a[i] = *(float4*)&As[(ty+16*i)*36+kk];
      #pragma unroll
      for (int j=0;j<4;j++) w[j] = *(float4*)&Bs[(tx+16*j)*36+kk];
      #pragma unroll
      for (int i=0;i<4;i++)
        #pragma unroll
        for (int j=0;j<4;j++)
          acc[i][j] += a[i].x*w[j].x + a[i].y*w[j].y + a[i].z*w[j].z + a[i].w*w[j].w;
    }
    __syncthreads();
  }
  #pragma unroll
  for (int i=0;i<4;i++){
    int b = bbase + ty + 16*i;
    #pragma unroll
    for (int j=0;j<4;j++){
      int jj = jbase + tx + 16*j;
      h0[(size_t)b*NH + jj] = acc[i][j] + bc[jj];
    }
  }
}

// ---------------- logits tile + partial argmax ----------------
// grid (NVT, BATCH/64), 256 thr. C[b,v]=dot(h[b],Wp[v]); writes per-(vtile,b) argmax partial.
__global__ __launch_bounds__(256) void k_pred(const float* __restrict__ h,
                                              const float* __restrict__ Wp,
                                              const float* __restrict__ bp,
                                              float* __restrict__ pval,
                                              int* __restrict__ pidx){
  __shared__ float As[64*36];
  __shared__ float Bs[64*36];
  __shared__ float rv[64*16];
  __shared__ int   ri[64*16];
  int tid = threadIdx.x;
  int tx = tid & 15, ty = tid >> 4;
  int vt = blockIdx.x;
  int vbase = vt * 64;
  int bbase = blockIdx.y * 64;
  int lrow = tid >> 3;
  int lc4  = (tid & 7) << 2;
  float acc[4][4] = {};
  for (int k0 = 0; k0 < NH; k0 += 32){
    #pragma unroll
    for (int rr = 0; rr < 64; rr += 32){
      *(float4*)&As[(lrow+rr)*36 + lc4] =
          *(const float4*)(h + (size_t)(bbase+lrow+rr)*NH + k0 + lc4);
      int v = vbase + lrow + rr;
      float4 wv = make_float4(0.f,0.f,0.f,0.f);
      if (v < NV) wv = *(const float4*)(Wp + (size_t)v*NH + k0 + lc4);
      *(float4*)&Bs[(lrow+rr)*36 + lc4] = wv;
    }
    __syncthreads();
    #pragma unroll
    for (int kk = 0; kk < 32; kk += 4){
      float4 a[4], w[4];
      #pragma unroll
      for (int i=0;i<4;i++) a[i] = *(float4*)&As[(ty+16*i)*36+kk];
      #pragma unroll
      for (int j=0;j<4;j++) w[j] = *(float4*)&Bs[(tx+16*j)*36+kk];
      #pragma unroll
      for (int i=0;i<4;i++)
        #pragma unroll
        for (int j=0;j<4;j++)
          acc[i][j] += a[i].x*w[j].x + a[i].y*w[j].y + a[i].z*w[j].z + a[i].w*w[j].w;
    }
    __syncthreads();
  }
  #pragma unroll
  for (int i=0;i<4;i++){
    int bl = ty + 16*i;
    float best = -INFINITY; int bidx = 0;
    #pragma unroll
    for (int j=0;j<4;j++){
      int v = vbase + tx + 16*j;
      if (v < NV){
        float val = acc[i][j] + bp[v];
        if (val > best){ best = val; bidx = v; }
      }
    }
    rv[bl*16+tx] = best; ri[bl*16+tx] = bidx;
  }
  __syncthreads();
  if (tid < 64){
    float best = -INFINITY; int bidx = 0;
    #pragma unroll
    for (int t=0;t<16;t++){
      float v = rv[tid*16+t];
      if (v > best){ best = v; bidx = ri[tid*16+t]; }
    }
    pval[vt*BATCH + bbase + tid] = best;
    pidx[vt*BATCH + bbase + tid] = bidx;
  }
}

// ---------------- argmax reduce -> token -> embed -> GRU cell ----------------
// grid (NH/16, BATCH/32), 256 thr. Each block: 16 j x 32 b outputs, all 6 dots fused.
__global__ __launch_bounds__(256) void k_gru(const int* __restrict__ cap,
    const float* __restrict__ pval, const int* __restrict__ pidx,
    const float* __restrict__ emb,
    const float* __restrict__ wih, const float* __restrict__ whh,
    const float* __restrict__ bih, const float* __restrict__ bhh,
    const float* __restrict__ hprev, float* __restrict__ hnew,
    int* __restrict__ preds, int use_caption, int pred_col){
  __shared__ int   s_tok[32];
  __shared__ float rav[32*8];
  __shared__ int   rai[32*8];
  __shared__ float xs[32*36];
  __shared__ float hs[32*36];
  __shared__ float wis[3*16*36];
  __shared__ float whs[3*16*36];
  int tid = threadIdx.x;
  int tx = tid & 15, ty = tid >> 4;
  int jbase = blockIdx.x * 16;
  int bbase = blockIdx.y * 32;

  // Phase A: resolve this block's 32 tokens
  if (use_caption){
    if (tid < 32) s_tok[tid] = cap[bbase + tid];
  } else {
    int bl = tid >> 3, l8 = tid & 7;
    float best = -INFINITY; int bidx = 0;
    for (int p = l8; p < NVT; p += 8){
      float v = pval[p*BATCH + bbase + bl];
      if (v > best){ best = v; bidx = pidx[p*BATCH + bbase + bl]; }
    }
    rav[bl*8 + l8] = best; rai[bl*8 + l8] = bidx;
    __syncthreads();
    if (tid < 32){
      float bb = -INFINITY; int bi = 0;
      #pragma unroll
      for (int t=0;t<8;t++){
        float v = rav[tid*8+t];
        if (v > bb){ bb = v; bi = rai[tid*8+t]; }
      }
      s_tok[tid] = bi;
      if (blockIdx.x == 0) preds[(bbase+tid)*NT + pred_col] = bi;
    }
  }
  __syncthreads();

  // Phase B/C: gi = x@wih^T, gh = h@whh^T (tile), then gate math
  float acc[2][6] = {};
  int lrow = tid >> 3;
  int lc4  = (tid & 7) << 2;
  for (int k0 = 0; k0 < NH; k0 += 32){
    int tokr = s_tok[lrow];
    *(float4*)&xs[lrow*36 + lc4] =
        *(const float4*)(emb + (size_t)tokr*NH + k0 + lc4);
    *(float4*)&hs[lrow*36 + lc4] =
        *(const float4*)(hprev + (size_t)(bbase+lrow)*NH + k0 + lc4);
    #pragma unroll
    for (int q = tid; q < 768; q += 256){
      int g  = q >> 7;           // 0..5
      int r  = (q >> 3) & 15;    // 0..15
      int cc = (q & 7) << 2;
      const float* wsrc = (g < 3) ? wih : whh;
      int gg = (g < 3) ? g : (g - 3);
      float* dst = (g < 3) ? wis : whs;
      *(float4*)&dst[gg*576 + r*36 + cc] =
          *(const float4*)(wsrc + (size_t)(gg*NH + jbase + r)*NH + k0 + cc);
    }
    __syncthreads();
    #pragma unroll
    for (int kk = 0; kk < 32; kk += 4){
      float4 x0 = *(float4*)&xs[ty*36+kk];
      float4 x1 = *(float4*)&xs[(ty+16)*36+kk];
      float4 h0v = *(float4*)&hs[ty*36+kk];
      float4 h1v = *(float4*)&hs[(ty+16)*36+kk];
      #pragma unroll
      for (int g=0; g<3; g++){
        float4 wi4 = *(float4*)&wis[g*576 + tx*36 + kk];
        float4 wh4 = *(float4*)&whs[g*576 + tx*36 + kk];
        acc[0][g]   += x0.x*wi4.x + x0.y*wi4.y + x0.z*wi4.z + x0.w*wi4.w;
        acc[1][g]   += x1.x*wi4.x + x1.y*wi4.y + x1.z*wi4.z + x1.w*wi4.w;
        acc[0][3+g] += h0v.x*wh4.x + h0v.y*wh4.y + h0v.z*wh4.z + h0v.w*wh4.w;
        acc[1][3+g] += h1v.x*wh4.x + h1v.y*wh4.y + h1v.z*wh4.z + h1v.w*wh4.w;
      }
    }
    __syncthreads();
  }
  int j = jbase + tx;
  float bi_r = bih[j], bi_z = bih[j+NH], bi_n = bih[j+2*NH];
  float bh_r = bhh[j], bh_z = bhh[j+NH], bh_n = bhh[j+2*NH];
  #pragma unroll
  for (int i=0;i<2;i++){
    int b = bbase + ty + 16*i;
    float r = 1.f/(1.f + expf(-((acc[i][0]+bi_r) + (acc[i][3]+bh_r))));
    float z = 1.f/(1.f + expf(-((acc[i][1]+bi_z) + (acc[i][4]+bh_z))));
    float n = tanhf((acc[i][2]+bi_n) + r*(acc[i][5]+bh_n));
    float hp = hprev[(size_t)b*NH + j];
    hnew[(size_t)b*NH + j] = (1.f - z)*n + z*hp;
  }
}

// ---------------- final argmax -> preds col 14 ----------------
__global__ void k_fin(const float* __restrict__ pval, const int* __restrict__ pidx,
                      int* __restrict__ preds, int col){
  __shared__ float rav[32*8];
  __shared__ int   rai[32*8];
  int tid = threadIdx.x;
  int bbase = blockIdx.x * 32;
  int bl = tid >> 3, l8 = tid & 7;
  float best = -INFINITY; int bidx = 0;
  for (int p = l8; p < NVT; p += 8){
    float v = pval[p*BATCH + bbase + bl];
    if (v > best){ best = v; bidx = pidx[p*BATCH + bbase + bl]; }
  }
  rav[bl*8+l8] = best; rai[bl*8+l8] = bidx;
  __syncthreads();
  if (tid < 32){
    float bb = -INFINITY; int bi = 0;
    #pragma unroll
    for (int t=0;t<8;t++){
      float v = rav[tid*8+t];
      if (v > bb){ bb = v; bi = rai[tid*8+t]; }
    }
    preds[(bbase+tid)*NT + col] = bi;
  }
}

extern "C" void kernel_launch(void* const* d_in, const int* in_sizes, int n_in,
                              void* d_out, int out_size, void* d_ws, size_t ws_size,
                              hipStream_t stream){
  const int*   cap = (const int*)d_in[0];
  const float* img = (const float*)d_in[1];
  const float* emb = (const float*)d_in[2];
  const float* Wc  = (const float*)d_in[3];
  const float* bc  = (const float*)d_in[4];
  const float* wih = (const float*)d_in[5];
  const float* whh = (const float*)d_in[6];
  const float* bih = (const float*)d_in[7];
  const float* bhh = (const float*)d_in[8];
  const float* Wp  = (const float*)d_in[9];
  const float* bp  = (const float*)d_in[10];
  int* preds = (int*)d_out;

  float* h0b  = (float*)d_ws;
  float* h1b  = h0b + BATCH*NH;
  float* pval = h1b + BATCH*NH;
  int*   pidx = (int*)(pval + NVT*BATCH);

  k_seed<<<1, 256, 0, stream>>>(cap, preds);
  k_h0<<<dim3(NH/64, BATCH/64), 256, 0, stream>>>(img, Wc, bc, h0b);
  float* hb[2] = {h0b, h1b};
  for (int s = 1; s <= NT-1; s++){
    const float* hprev = hb[(s-1)&1];
    float* hnew = hb[s&1];
    k_gru<<<dim3(NH/16, BATCH/32), 256, 0, stream>>>(cap, pval, pidx, emb, wih, whh,
                                                     bih, bhh, hprev, hnew, preds,
                                                     (s==1)?1:0, s-1);
    k_pred<<<dim3(NVT, BATCH/64), 256, 0, stream>>>(hnew, Wp, bp, pval, pidx);
  }
  k_fin<<<dim3(BATCH/32), 256, 0, stream>>>(pval, pidx, preds, NT-1);
}

// Round 2
// 1628.866 us; speedup vs baseline: 2.2543x; 2.2543x over previous
//
#include <hip/hip_runtime.h>
#include <math.h>

#define BATCH 256
#define NH 512
#define NCOND 1024
#define NV 32002
#define NT 15
#define NVT_F32 501   // ceil(NV/64)  (fallback fp32 path)
#define NVT_MF  251   // ceil(NV/128) (MFMA path)

typedef short short8 __attribute__((ext_vector_type(8)));
typedef float float4v __attribute__((ext_vector_type(4)));

__device__ __forceinline__ void async_load16(const void* g, void* l){
  __builtin_amdgcn_global_load_lds(
      (const __attribute__((address_space(1))) void*)g,
      (__attribute__((address_space(3))) void*)l, 16, 0, 0);
}

__device__ __forceinline__ void split2(float x, unsigned short& hi, unsigned short& lo){
  unsigned u = __float_as_uint(x);
  unsigned r = u + 0x7fffu + ((u >> 16) & 1u);
  hi = (unsigned short)(r >> 16);
  float fh = __uint_as_float(r & 0xffff0000u);
  float res = x - fh;
  unsigned u2 = __float_as_uint(res);
  unsigned r2 = u2 + 0x7fffu + ((u2 >> 16) & 1u);
  lo = (unsigned short)(r2 >> 16);
}

// ---------------- seed token -> preds col 0 ----------------
__global__ void k_seed(const int* __restrict__ cap, int* __restrict__ preds){
  int b = threadIdx.x;
  preds[b*NT + 0] = cap[b];
}

// ---------------- split W_pred fp32 -> (hi, lo) bf16 ----------------
// grid 16001 x 256 thr x float4 : 16001*1024 = NV*NH exactly
__global__ __launch_bounds__(256) void k_split_w(const float* __restrict__ W,
                                                 unsigned short* __restrict__ Whi,
                                                 unsigned short* __restrict__ Wlo){
  size_t i = ((size_t)blockIdx.x * 256 + threadIdx.x) * 4;
  float4 v = *(const float4*)(W + i);
  unsigned short h0,l0,h1,l1,h2,l2,h3,l3;
  split2(v.x,h0,l0); split2(v.y,h1,l1); split2(v.z,h2,l2); split2(v.w,h3,l3);
  ushort4 hs = {h0,h1,h2,h3};
  ushort4 ls = {l0,l1,l2,l3};
  *(ushort4*)(Whi + i) = hs;
  *(ushort4*)(Wlo + i) = ls;
}

// ---------------- h0 = img @ W_cond^T + b_cond (+ split) ----------------
__global__ __launch_bounds__(256) void k_h0(const float* __restrict__ img,
                                            const float* __restrict__ Wc,
                                            const float* __restrict__ bc,
                                            float* __restrict__ h0,
                                            unsigned short* __restrict__ hhi,
                                            unsigned short* __restrict__ hlo,
                                            int do_split){
  __shared__ float As[64*36];
  __shared__ float Bs[64*36];
  int tid = threadIdx.x;
  int tx = tid & 15, ty = tid >> 4;
  int jbase = blockIdx.x * 64;
  int bbase = blockIdx.y * 64;
  int lrow = tid >> 3;
  int lc4  = (tid & 7) << 2;
  float acc[4][4] = {};
  for (int k0 = 0; k0 < NCOND; k0 += 32){
    #pragma unroll
    for (int rr = 0; rr < 64; rr += 32){
      *(float4*)&As[(lrow+rr)*36 + lc4] =
          *(const float4*)(img + (size_t)(bbase+lrow+rr)*NCOND + k0 + lc4);
      *(float4*)&Bs[(lrow+rr)*36 + lc4] =
          *(const float4*)(Wc + (size_t)(jbase+lrow+rr)*NCOND + k0 + lc4);
    }
    __syncthreads();
    #pragma unroll
    for (int kk = 0; kk < 32; kk += 4){
      float4 a[4], w[4];
      #pragma unroll
      for (int i=0;i<4;i++) a[i] = *(float4*)&As[(ty+16*i)*36+kk];
      #pragma unroll
      for (int j=0;j<4;j++) w[j] = *(float4*)&Bs[(tx+16*j)*36+kk];
      #pragma unroll
      for (int i=0;i<4;i++)
        #pragma unroll
        for (int j=0;j<4;j++)
          acc[i][j] += a[i].x*w[j].x + a[i].y*w[j].y + a[i].z*w[j].z + a[i].w*w[j].w;
    }
    __syncthreads();
  }
  #pragma unroll
  for (int i=0;i<4;i++){
    int b = bbase + ty + 16*i;
    #pragma unroll
    for (int j=0;j<4;j++){
      int jj = jbase + tx + 16*j;
      float val = acc[i][j] + bc[jj];
      h0[(size_t)b*NH + jj] = val;
      if (do_split){
        unsigned short h,l; split2(val,h,l);
        hhi[(size_t)b*NH + jj] = h;
        hlo[(size_t)b*NH + jj] = l;
      }
    }
  }
}

// ---------------- MFMA logits tile + partial argmax ----------------
// grid (NVT_MF, 2), 256 thr. C[v,b] over 128x128 tile, split-bf16 3-MFMA.
__global__ __launch_bounds__(256) void k_pred_mfma(
    const unsigned short* __restrict__ Hhi, const unsigned short* __restrict__ Hlo,
    const unsigned short* __restrict__ Whi, const unsigned short* __restrict__ Wlo,
    const float* __restrict__ bp,
    float* __restrict__ pval, int* __restrict__ pidx)
{
  __shared__ __align__(16) unsigned short sAh[128*32];
  __shared__ __align__(16) unsigned short sAl[128*32];
  __shared__ __align__(16) unsigned short sBh[128*32];
  __shared__ __align__(16) unsigned short sBl[128*32];
  __shared__ float sval[256];
  __shared__ int   sidx[256];

  int tid = threadIdx.x;
  int w = tid >> 6, lane = tid & 63;
  int vt = blockIdx.x, vbase = vt * 128;
  int bbase = blockIdx.y * 128;
  int mhalf = w & 1, nhalf = w >> 1;

  // staging: wave w stages buffer w
  unsigned short* mybuf = (w==0)?sAh : (w==1)?sAl : (w==2)?sBh : sBl;
  const unsigned short* gsrc = (w==0)?Whi : (w==1)?Wlo : (w==2)?Hhi : Hlo;
  int rowbase = (w < 2) ? vbase : bbase;
  int isA = (w < 2);

  int rl = lane >> 2;                       // row-in-pass
  int sl = lane & 3;                        // slot
  int qq = (sl - ((lane >> 3) & 3)) & 3;    // kpart this lane fetches

  float4v acc[4][4];
  #pragma unroll
  for (int mi=0;mi<4;mi++)
    #pragma unroll
    for (int ni=0;ni<4;ni++)
      acc[mi][ni] = (float4v){0.f,0.f,0.f,0.f};

  int q = lane >> 4, b16 = lane & 15;

  for (int k0 = 0; k0 < NH; k0 += 32){
    #pragma unroll
    for (int t = 0; t < 8; t++){
      int grow = rowbase + t*16 + rl;
      if (isA && grow > NV-1) grow = NV-1;
      const unsigned short* gp = gsrc + (size_t)grow*NH + k0 + qq*8;
      async_load16(gp, (char*)mybuf + t*1024);
    }
    __syncthreads();
    short8 ah[4], al[4], bh[4], bl[4];
    #pragma unroll
    for (int mi=0;mi<4;mi++){
      int r = mhalf*64 + mi*16 + b16;
      int p = (q + (r>>1)) & 3;
      int off = r*64 + p*16;
      ah[mi] = *(const short8*)((const char*)sAh + off);
      al[mi] = *(const short8*)((const char*)sAl + off);
    }
    #pragma unroll
    for (int ni=0;ni<4;ni++){
      int r = nhalf*64 + ni*16 + b16;
      int p = (q + (r>>1)) & 3;
      int off = r*64 + p*16;
      bh[ni] = *(const short8*)((const char*)sBh + off);
      bl[ni] = *(const short8*)((const char*)sBl + off);
    }
    #pragma unroll
    for (int mi=0;mi<4;mi++)
      #pragma unroll
      for (int ni=0;ni<4;ni++){
        acc[mi][ni] = __builtin_amdgcn_mfma_f32_16x16x32_bf16(ah[mi], bh[ni], acc[mi][ni], 0,0,0);
        acc[mi][ni] = __builtin_amdgcn_mfma_f32_16x16x32_bf16(ah[mi], bl[ni], acc[mi][ni], 0,0,0);
        acc[mi][ni] = __builtin_amdgcn_mfma_f32_16x16x32_bf16(al[mi], bh[ni], acc[mi][ni], 0,0,0);
      }
    __syncthreads();
  }

  // epilogue: per-lane argmax over 16 vocab rows (x4 ni), bias fused
  float bestv[4] = {-INFINITY,-INFINITY,-INFINITY,-INFINITY};
  int   besti[4] = {0x7fffffff,0x7fffffff,0x7fffffff,0x7fffffff};
  #pragma unroll
  for (int mi=0;mi<4;mi++){
    #pragma unroll
    for (int reg=0;reg<4;reg++){
      int v = vbase + mhalf*64 + mi*16 + q*4 + reg;
      if (v < NV){
        float bpv = bp[v];
        #pragma unroll
        for (int ni=0;ni<4;ni++){
          float cand = acc[mi][ni][reg] + bpv;
          if (cand > bestv[ni] || (cand == bestv[ni] && v < besti[ni])){
            bestv[ni] = cand; besti[ni] = v;
          }
        }
      }
    }
  }
  #pragma unroll
  for (int ni=0;ni<4;ni++){
    #pragma unroll
    for (int off=16; off<=32; off<<=1){
      float ov = __shfl_xor(bestv[ni], off);
      int   oi = __shfl_xor(besti[ni], off);
      if (ov > bestv[ni] || (ov == bestv[ni] && oi < besti[ni])){
        bestv[ni] = ov; besti[ni] = oi;
      }
    }
    if (lane < 16){
      sval[w*64 + ni*16 + b16] = bestv[ni];
      sidx[w*64 + ni*16 + b16] = besti[ni];
    }
  }
  __syncthreads();
  if (tid < 128){
    int nh = tid >> 6;
    int wA = nh*2, wB = nh*2 + 1;
    int slot = (tid & 63);
    float vA = sval[wA*64 + slot], vB = sval[wB*64 + slot];
    int   iA = sidx[wA*64 + slot], iB = sidx[wB*64 + slot];
    bool takeB = (vB > vA) || (vB == vA && iB < iA);
    pval[vt*BATCH + bbase + tid] = takeB ? vB : vA;
    pidx[vt*BATCH + bbase + tid] = takeB ? iB : iA;
  }
}

// ---------------- fp32 logits tile + partial argmax (fallback) ----------------
__global__ __launch_bounds__(256) void k_pred_f32(const float* __restrict__ h,
                                              const float* __restrict__ Wp,
                                              const float* __restrict__ bp,
                                              float* __restrict__ pval,
                                              int* __restrict__ pidx){
  __shared__ float As[64*36];
  __shared__ float Bs[64*36];
  __shared__ float rv[64*16];
  __shared__ int   ri[64*16];
  int tid = threadIdx.x;
  int tx = tid & 15, ty = tid >> 4;
  int vt = blockIdx.x;
  int vbase = vt * 64;
  int bbase = blockIdx.y * 64;
  int lrow = tid >> 3;
  int lc4  = (tid & 7) << 2;
  float acc[4][4] = {};
  for (int k0 = 0; k0 < NH; k0 += 32){
    #pragma unroll
    for (int rr = 0; rr < 64; rr += 32){
      *(float4*)&As[(lrow+rr)*36 + lc4] =
          *(const float4*)(h + (size_t)(bbase+lrow+rr)*NH + k0 + lc4);
      int v = vbase + lrow + rr;
      float4 wv = make_float4(0.f,0.f,0.f,0.f);
      if (v < NV) wv = *(const float4*)(Wp + (size_t)v*NH + k0 + lc4);
      *(float4*)&Bs[(lrow+rr)*36 + lc4] = wv;
    }
    __syncthreads();
    #pragma unroll
    for (int kk = 0; kk < 32; kk += 4){
      float4 a[4], wv[4];
      #pragma unroll
      for (int i=0;i<4;i++) a[i] = *(float4*)&As[(ty+16*i)*36+kk];
      #pragma unroll
      for (int j=0;j<4;j++) wv[j] = *(float4*)&Bs[(tx+16*j)*36+kk];
      #pragma unroll
      for (int i=0;i<4;i++)
        #pragma unroll
        for (int j=0;j<4;j++)
          acc[i][j] += a[i].x*wv[j].x + a[i].y*wv[j].y + a[i].z*wv[j].z + a[i].w*wv[j].w;
    }
    __syncthreads();
  }
  #pragma unroll
  for (int i=0;i<4;i++){
    int bl = ty + 16*i;
    float best = -INFINITY; int bidx = 0;
    #pragma unroll
    for (int j=0;j<4;j++){
      int v = vbase + tx + 16*j;
      if (v < NV){
        float val = acc[i][j] + bp[v];
        if (val > best){ best = val; bidx = v; }
      }
    }
    rv[bl*16+tx] = best; ri[bl*16+tx] = bidx;
  }
  __syncthreads();
  if (tid < 64){
    float best = -INFINITY; int bidx = 0;
    #pragma unroll
    for (int t=0;t<16;t++){
      float v = rv[tid*16+t];
      if (v > best){ best = v; bidx = ri[tid*16+t]; }
    }
    pval[vt*BATCH + bbase + tid] = best;
    pidx[vt*BATCH + bbase + tid] = bidx;
  }
}

// ---------------- argmax reduce -> token -> embed -> GRU cell ----------------
__global__ __launch_bounds__(256) void k_gru(const int* __restrict__ cap,
    const float* __restrict__ pval, const int* __restrict__ pidx,
    const float* __restrict__ emb,
    const float* __restrict__ wih, const float* __restrict__ whh,
    const float* __restrict__ bih, const float* __restrict__ bhh,
    const float* __restrict__ hprev, float* __restrict__ hnew,
    unsigned short* __restrict__ hhi, unsigned short* __restrict__ hlo,
    int* __restrict__ preds, int use_caption, int pred_col, int nvt, int do_split){
  __shared__ int   s_tok[32];
  __shared__ float rav[32*8];
  __shared__ int   rai[32*8];
  __shared__ float xs[32*36];
  __shared__ float hs[32*36];
  __shared__ float wis[3*16*36];
  __shared__ float whs[3*16*36];
  int tid = threadIdx.x;
  int tx = tid & 15, ty = tid >> 4;
  int jbase = blockIdx.x * 16;
  int bbase = blockIdx.y * 32;

  if (use_caption){
    if (tid < 32) s_tok[tid] = cap[bbase + tid];
  } else {
    int bl = tid >> 3, l8 = tid & 7;
    float best = -INFINITY; int bidx = 0x7fffffff;
    for (int p = l8; p < nvt; p += 8){
      float v = pval[p*BATCH + bbase + bl];
      int   i = pidx[p*BATCH + bbase + bl];
      if (v > best || (v == best && i < bidx)){ best = v; bidx = i; }
    }
    rav[bl*8 + l8] = best; rai[bl*8 + l8] = bidx;
    __syncthreads();
    if (tid < 32){
      float bb = -INFINITY; int bi = 0x7fffffff;
      #pragma unroll
      for (int t=0;t<8;t++){
        float v = rav[tid*8+t]; int i = rai[tid*8+t];
        if (v > bb || (v == bb && i < bi)){ bb = v; bi = i; }
      }
      s_tok[tid] = bi;
      if (blockIdx.x == 0) preds[(bbase+tid)*NT + pred_col] = bi;
    }
  }
  __syncthreads();

  float acc[2][6] = {};
  int lrow = tid >> 3;
  int lc4  = (tid & 7) << 2;
  for (int k0 = 0; k0 < NH; k0 += 32){
    int tokr = s_tok[lrow];
    *(float4*)&xs[lrow*36 + lc4] =
        *(const float4*)(emb + (size_t)tokr*NH + k0 + lc4);
    *(float4*)&hs[lrow*36 + lc4] =
        *(const float4*)(hprev + (size_t)(bbase+lrow)*NH + k0 + lc4);
    #pragma unroll
    for (int qy = tid; qy < 768; qy += 256){
      int g  = qy >> 7;
      int r  = (qy >> 3) & 15;
      int cc = (qy & 7) << 2;
      const float* wsrc = (g < 3) ? wih : whh;
      int gg = (g < 3) ? g : (g - 3);
      float* dst = (g < 3) ? wis : whs;
      *(float4*)&dst[gg*576 + r*36 + cc] =
          *(const float4*)(wsrc + (size_t)(gg*NH + jbase + r)*NH + k0 + cc);
    }
    __syncthreads();
    #pragma unroll
    for (int kk = 0; kk < 32; kk += 4){
      float4 x0 = *(float4*)&xs[ty*36+kk];
      float4 x1 = *(float4*)&xs[(ty+16)*36+kk];
      float4 h0v = *(float4*)&hs[ty*36+kk];
      float4 h1v = *(float4*)&hs[(ty+16)*36+kk];
      #pragma unroll
      for (int g=0; g<3; g++){
        float4 wi4 = *(float4*)&wis[g*576 + tx*36 + kk];
        float4 wh4 = *(float4*)&whs[g*576 + tx*36 + kk];
        acc[0][g]   += x0.x*wi4.x + x0.y*wi4.y + x0.z*wi4.z + x0.w*wi4.w;
        acc[1][g]   += x1.x*wi4.x + x1.y*wi4.y + x1.z*wi4.z + x1.w*wi4.w;
        acc[0][3+g] += h0v.x*wh4.x + h0v.y*wh4.y + h0v.z*wh4.z + h0v.w*wh4.w;
        acc[1][3+g] += h1v.x*wh4.x + h1v.y*wh4.y + h1v.z*wh4.z + h1v.w*wh4.w;
      }
    }
    __syncthreads();
  }
  int j = jbase + tx;
  float bi_r = bih[j], bi_z = bih[j+NH], bi_n = bih[j+2*NH];
  float bh_r = bhh[j], bh_z = bhh[j+NH], bh_n = bhh[j+2*NH];
  #pragma unroll
  for (int i=0;i<2;i++){
    int b = bbase + ty + 16*i;
    float r = 1.f/(1.f + expf(-((acc[i][0]+bi_r) + (acc[i][3]+bh_r))));
    float z = 1.f/(1.f + expf(-((acc[i][1]+bi_z) + (acc[i][4]+bh_z))));
    float n = tanhf((acc[i][2]+bi_n) + r*(acc[i][5]+bh_n));
    float hp = hprev[(size_t)b*NH + j];
    float val = (1.f - z)*n + z*hp;
    hnew[(size_t)b*NH + j] = val;
    if (do_split){
      unsigned short h,l; split2(val,h,l);
      hhi[(size_t)b*NH + j] = h;
      hlo[(size_t)b*NH + j] = l;
    }
  }
}

// ---------------- final argmax -> preds col 14 ----------------
__global__ void k_fin(const float* __restrict__ pval, const int* __restrict__ pidx,
                      int* __restrict__ preds, int col, int nvt){
  __shared__ float rav[32*8];
  __shared__ int   rai[32*8];
  int tid = threadIdx.x;
  int bbase = blockIdx.x * 32;
  int bl = tid >> 3, l8 = tid & 7;
  float best = -INFINITY; int bidx = 0x7fffffff;
  for (int p = l8; p < nvt; p += 8){
    float v = pval[p*BATCH + bbase + bl];
    int   i = pidx[p*BATCH + bbase + bl];
    if (v > best || (v == best && i < bidx)){ best = v; bidx = i; }
  }
  rav[bl*8+l8] = best; rai[bl*8+l8] = bidx;
  __syncthreads();
  if (tid < 32){
    float bb = -INFINITY; int bi = 0x7fffffff;
    #pragma unroll
    for (int t=0;t<8;t++){
      float v = rav[tid*8+t]; int i = rai[tid*8+t];
      if (v > bb || (v == bb && i < bi)){ bb = v; bi = i; }
    }
    preds[(bbase+tid)*NT + col] = bi;
  }
}

extern "C" void kernel_launch(void* const* d_in, const int* in_sizes, int n_in,
                              void* d_out, int out_size, void* d_ws, size_t ws_size,
                              hipStream_t stream){
  const int*   cap = (const int*)d_in[0];
  const float* img = (const float*)d_in[1];
  const float* emb = (const float*)d_in[2];
  const float* Wc  = (const float*)d_in[3];
  const float* bc  = (const float*)d_in[4];
  const float* wih = (const float*)d_in[5];
  const float* whh = (const float*)d_in[6];
  const float* bih = (const float*)d_in[7];
  const float* bhh = (const float*)d_in[8];
  const float* Wp  = (const float*)d_in[9];
  const float* bp  = (const float*)d_in[10];
  int* preds = (int*)d_out;

  char* p = (char*)d_ws;
  float* h0b = (float*)p;            p += (size_t)BATCH*NH*4;
  float* h1b = (float*)p;            p += (size_t)BATCH*NH*4;
  float* pval = (float*)p;           p += (size_t)NVT_F32*BATCH*4;
  int*   pidx = (int*)p;             p += (size_t)NVT_F32*BATCH*4;
  unsigned short* Hhi = (unsigned short*)p; p += (size_t)BATCH*NH*2;
  unsigned short* Hlo = (unsigned short*)p; p += (size_t)BATCH*NH*2;
  unsigned short* Whi = (unsigned short*)p; p += (size_t)NV*NH*2;
  unsigned short* Wlo = (unsigned short*)p; p += (size_t)NV*NH*2;
  size_t need = (size_t)(p - (char*)d_ws);

  bool use_mfma = (ws_size >= need);

  k_seed<<<1, 256, 0, stream>>>(cap, preds);
  float* hb[2] = {h0b, h1b};

  if (use_mfma){
    k_split_w<<<dim3(16001), 256, 0, stream>>>(Wp, Whi, Wlo);
    k_h0<<<dim3(NH/64, BATCH/64), 256, 0, stream>>>(img, Wc, bc, h0b, Hhi, Hlo, 1);
    for (int s = 1; s <= NT-1; s++){
      const float* hprev = hb[(s-1)&1];
      float* hnew = hb[s&1];
      k_gru<<<dim3(NH/16, BATCH/32), 256, 0, stream>>>(cap, pval, pidx, emb, wih, whh,
                                                       bih, bhh, hprev, hnew, Hhi, Hlo,
                                                       preds, (s==1)?1:0, s-1, NVT_MF, 1);
      k_pred_mfma<<<dim3(NVT_MF, 2), 256, 0, stream>>>(Hhi, Hlo, Whi, Wlo, bp, pval, pidx);
    }
    k_fin<<<dim3(BATCH/32), 256, 0, stream>>>(pval, pidx, preds, NT-1, NVT_MF);
  } else {
    k_h0<<<dim3(NH/64, BATCH/64), 256, 0, stream>>>(img, Wc, bc, h0b, Hhi, Hlo, 0);
    for (int s = 1; s <= NT-1; s++){
      const float* hprev = hb[(s-1)&1];
      float* hnew = hb[s&1];
      k_gru<<<dim3(NH/16, BATCH/32), 256, 0, stream>>>(cap, pval, pidx, emb, wih, whh,
                                                       bih, bhh, hprev, hnew, Hhi, Hlo,
                                                       preds, (s==1)?1:0, s-1, NVT_F32, 0);
      k_pred_f32<<<dim3(NVT_F32, BATCH/64), 256, 0, stream>>>(hnew, Wp, bp, pval, pidx);
    }
    k_fin<<<dim3(BATCH/32), 256, 0, stream>>>(pval, pidx, preds, NT-1, NVT_F32);
  }
}

// Round 3
// 1176.202 us; speedup vs baseline: 3.1219x; 1.3849x over previous
//
#include <hip/hip_runtime.h>
#include <math.h>

#define BATCH 256
#define NH 512
#define NCOND 1024
#define NV 32002
#define NT 15
#define NVT_F32 501   // ceil(NV/64)  (fallback fp32 path)
#define NVT_MF  251   // ceil(NV/128) (MFMA path)

// split-table section sizes in float4 units
#define SP_P  4096256   // NV*NH/4
#define SP_IH 196608    // 1536*512/4
#define SP_HH 196608
#define SP_C  131072    // 512*1024/4
#define SPLIT_BLOCKS 18049  // (SP_P+SP_IH+SP_HH+SP_C)/256

typedef short short8 __attribute__((ext_vector_type(8)));
typedef float float4v __attribute__((ext_vector_type(4)));

__device__ __forceinline__ void async_load16(const void* g, void* l){
  __builtin_amdgcn_global_load_lds(
      (const __attribute__((address_space(1))) void*)g,
      (__attribute__((address_space(3))) void*)l, 16, 0, 0);
}

__device__ __forceinline__ void split2(float x, unsigned short& hi, unsigned short& lo){
  unsigned u = __float_as_uint(x);
  unsigned r = u + 0x7fffu + ((u >> 16) & 1u);
  hi = (unsigned short)(r >> 16);
  float fh = __uint_as_float(r & 0xffff0000u);
  float res = x - fh;
  unsigned u2 = __float_as_uint(res);
  unsigned r2 = u2 + 0x7fffu + ((u2 >> 16) & 1u);
  lo = (unsigned short)(r2 >> 16);
}

// ---------------- seed token -> preds col 0 ----------------
__global__ void k_seed(const int* __restrict__ cap, int* __restrict__ preds){
  int b = threadIdx.x;
  preds[b*NT + 0] = cap[b];
}

// ---------------- split W_pred + [wih;whh] + W_cond fp32 -> bf16 hi/lo ----------------
__global__ __launch_bounds__(256) void k_split_all(
    const float* __restrict__ Wp, const float* __restrict__ wih,
    const float* __restrict__ whh, const float* __restrict__ Wc,
    unsigned short* __restrict__ Whi, unsigned short* __restrict__ Wlo,
    unsigned short* __restrict__ W6hi, unsigned short* __restrict__ W6lo,
    unsigned short* __restrict__ Wchi, unsigned short* __restrict__ Wclo){
  size_t i = (size_t)blockIdx.x * 256 + threadIdx.x;
  const float* src; unsigned short *dh, *dl; size_t off;
  if (i < SP_P){ src = Wp; dh = Whi; dl = Wlo; off = i; }
  else if (i < SP_P + SP_IH){ src = wih; dh = W6hi; dl = W6lo; off = i - SP_P; }
  else if (i < SP_P + SP_IH + SP_HH){
    src = whh; dh = W6hi + 786432; dl = W6lo + 786432; off = i - SP_P - SP_IH;
  } else { src = Wc; dh = Wchi; dl = Wclo; off = i - SP_P - SP_IH - SP_HH; }
  float4 v = *(const float4*)(src + off*4);
  unsigned short h0,l0,h1,l1,h2,l2,h3,l3;
  split2(v.x,h0,l0); split2(v.y,h1,l1); split2(v.z,h2,l2); split2(v.w,h3,l3);
  ushort4 hs = {h0,h1,h2,h3};
  ushort4 ls = {l0,l1,l2,l3};
  *(ushort4*)(dh + off*4) = hs;
  *(ushort4*)(dl + off*4) = ls;
}

// ---------------- h0 = img @ W_cond^T + b_cond  (MFMA split-bf16) ----------------
// grid (32, 4): 16 j x 64 b per block, K=1024, BK=64.
__global__ __launch_bounds__(256) void k_h0_mf(
    const float* __restrict__ img,
    const unsigned short* __restrict__ Wchi, const unsigned short* __restrict__ Wclo,
    const float* __restrict__ bc,
    float* __restrict__ h0,
    unsigned short* __restrict__ hhi, unsigned short* __restrict__ hlo){
  __shared__ __align__(16) unsigned short sA[2][16*64];
  __shared__ __align__(16) unsigned short sB[2][64*64];
  int tid = threadIdx.x, w = tid >> 6, lane = tid & 63;
  int jbase = blockIdx.x * 16, bbase = blockIdx.y * 64;
  int r16 = lane & 15, q = lane >> 4;
  float4v acc = {0.f,0.f,0.f,0.f};
  for (int k0 = 0; k0 < NCOND; k0 += 64){
    { // A: 4 passes total, wave w does pass w
      int arr = w >> 1, t = w & 1;
      int a = t*8 + (lane >> 3);
      int p = (lane & 7) ^ (lane >> 3);
      const unsigned short* gs = (arr ? Wclo : Wchi) + (size_t)(jbase + a)*NCOND + k0 + p*8;
      async_load16(gs, (char*)&sA[arr][0] + t*1024);
    }
    #pragma unroll
    for (int i = 0; i < 2; i++){ // B: img fp32 -> split -> LDS
      int u = tid + 256*i;
      int b = u >> 3, s = u & 7;
      int p = s ^ (b & 7);
      const float* gp = img + (size_t)(bbase + b)*NCOND + k0 + p*8;
      float4 f0 = *(const float4*)gp, f1 = *(const float4*)(gp + 4);
      short8 hv, lv; unsigned short hh, ll;
      split2(f0.x,hh,ll); hv[0]=(short)hh; lv[0]=(short)ll;
      split2(f0.y,hh,ll); hv[1]=(short)hh; lv[1]=(short)ll;
      split2(f0.z,hh,ll); hv[2]=(short)hh; lv[2]=(short)ll;
      split2(f0.w,hh,ll); hv[3]=(short)hh; lv[3]=(short)ll;
      split2(f1.x,hh,ll); hv[4]=(short)hh; lv[4]=(short)ll;
      split2(f1.y,hh,ll); hv[5]=(short)hh; lv[5]=(short)ll;
      split2(f1.z,hh,ll); hv[6]=(short)hh; lv[6]=(short)ll;
      split2(f1.w,hh,ll); hv[7]=(short)hh; lv[7]=(short)ll;
      *(short8*)((char*)&sB[0][0] + b*128 + s*16) = hv;
      *(short8*)((char*)&sB[1][0] + b*128 + s*16) = lv;
    }
    __syncthreads();
    int rb = w*16 + r16;
    #pragma unroll
    for (int kh = 0; kh < 2; kh++){
      int pa = kh*4 + q;
      int offA = r16*128 + ((pa ^ (r16 & 7))*16);
      int offB = rb*128 + ((pa ^ (rb & 7))*16);
      short8 ah = *(const short8*)((const char*)&sA[0][0] + offA);
      short8 al = *(const short8*)((const char*)&sA[1][0] + offA);
      short8 bh = *(const short8*)((const char*)&sB[0][0] + offB);
      short8 bl = *(const short8*)((const char*)&sB[1][0] + offB);
      acc = __builtin_amdgcn_mfma_f32_16x16x32_bf16(ah, bh, acc, 0,0,0);
      acc = __builtin_amdgcn_mfma_f32_16x16x32_bf16(ah, bl, acc, 0,0,0);
      acc = __builtin_amdgcn_mfma_f32_16x16x32_bf16(al, bh, acc, 0,0,0);
    }
    __syncthreads();
  }
  int b = bbase + w*16 + r16;
  #pragma unroll
  for (int reg = 0; reg < 4; reg++){
    int j = jbase + q*4 + reg;
    float val = acc[reg] + bc[j];
    h0[(size_t)b*NH + j] = val;
    unsigned short sh, sl; split2(val, sh, sl);
    hhi[(size_t)b*NH + j] = sh;
    hlo[(size_t)b*NH + j] = sl;
  }
}

// ---------------- fused: argmax-resolve -> embed-gather/split -> GRU (MFMA) ----------------
// grid (32, 4): 16 hidden-j x 64 b per block, 6 gate tiles, K=512, BK=64.
__global__ __launch_bounds__(256) void k_gru_mf(
    const int* __restrict__ cap,
    const float* __restrict__ pval, const int* __restrict__ pidx,
    const float* __restrict__ emb,
    const unsigned short* __restrict__ W6hi, const unsigned short* __restrict__ W6lo,
    const unsigned short* __restrict__ Hhi, const unsigned short* __restrict__ Hlo,
    const float* __restrict__ bih, const float* __restrict__ bhh,
    const float* __restrict__ hprev, float* __restrict__ hnew,
    unsigned short* __restrict__ nhhi, unsigned short* __restrict__ nhlo,
    int* __restrict__ preds, int use_caption, int pred_col){
  __shared__ __align__(16) unsigned short sA[2][96*64];
  __shared__ __align__(16) unsigned short sX[2][64*64];
  __shared__ __align__(16) unsigned short sH[2][64*64];
  __shared__ int tok[64];
  __shared__ float rav[256];
  __shared__ int   rai[256];
  int tid = threadIdx.x, w = tid >> 6, lane = tid & 63;
  int jbase = blockIdx.x * 16, bbase = blockIdx.y * 64;

  if (use_caption){
    if (tid < 64) tok[tid] = cap[bbase + tid];
    __syncthreads();
  } else {
    int b = tid >> 2, pp = tid & 3;
    float best = -INFINITY; int bidx = 0x7fffffff;
    for (int p = pp; p < NVT_MF; p += 4){
      float v = pval[p*BATCH + bbase + b];
      int  ix = pidx[p*BATCH + bbase + b];
      if (v > best || (v == best && ix < bidx)){ best = v; bidx = ix; }
    }
    rav[tid] = best; rai[tid] = bidx;
    __syncthreads();
    if (tid < 64){
      float bb = rav[tid*4]; int bi = rai[tid*4];
      #pragma unroll
      for (int t = 1; t < 4; t++){
        float v = rav[tid*4+t]; int ix = rai[tid*4+t];
        if (v > bb || (v == bb && ix < bi)){ bb = v; bi = ix; }
      }
      tok[tid] = bi;
      if (blockIdx.x == 0) preds[(bbase + tid)*NT + pred_col] = bi;
    }
    __syncthreads();
  }

  float4v acc[6];
  #pragma unroll
  for (int g = 0; g < 6; g++) acc[g] = (float4v){0.f,0.f,0.f,0.f};
  int r16 = lane & 15, q = lane >> 4;

  for (int k0 = 0; k0 < NH; k0 += 64){
    #pragma unroll
    for (int i = 0; i < 6; i++){ // A: W6 rows, 24 passes
      int ps = w*6 + i;
      int arr = ps / 12, t = ps % 12;
      int a = t*8 + (lane >> 3);
      int g = a >> 4, rr = a & 15;
      int p = (lane & 7) ^ (a & 7);
      const unsigned short* gs = (arr ? W6lo : W6hi)
          + (size_t)(g*NH + jbase + rr)*NH + k0 + p*8;
      async_load16(gs, (char*)&sA[arr][0] + t*1024);
    }
    #pragma unroll
    for (int i = 0; i < 4; i++){ // H: pre-split hidden, 16 passes
      int ps = w*4 + i;
      int arr = ps >> 3, t = ps & 7;
      int a = t*8 + (lane >> 3);
      int p = (lane & 7) ^ (lane >> 3);
      const unsigned short* gs = (arr ? Hlo : Hhi) + (size_t)(bbase + a)*NH + k0 + p*8;
      async_load16(gs, (char*)&sH[arr][0] + t*1024);
    }
    #pragma unroll
    for (int i = 0; i < 2; i++){ // X: emb gather fp32 -> split -> LDS
      int u = tid + 256*i;
      int b = u >> 3, s = u & 7;
      int p = s ^ (b & 7);
      const float* gp = emb + (size_t)tok[b]*NH + k0 + p*8;
      float4 f0 = *(const float4*)gp, f1 = *(const float4*)(gp + 4);
      short8 hv, lv; unsigned short hh, ll;
      split2(f0.x,hh,ll); hv[0]=(short)hh; lv[0]=(short)ll;
      split2(f0.y,hh,ll); hv[1]=(short)hh; lv[1]=(short)ll;
      split2(f0.z,hh,ll); hv[2]=(short)hh; lv[2]=(short)ll;
      split2(f0.w,hh,ll); hv[3]=(short)hh; lv[3]=(short)ll;
      split2(f1.x,hh,ll); hv[4]=(short)hh; lv[4]=(short)ll;
      split2(f1.y,hh,ll); hv[5]=(short)hh; lv[5]=(short)ll;
      split2(f1.z,hh,ll); hv[6]=(short)hh; lv[6]=(short)ll;
      split2(f1.w,hh,ll); hv[7]=(short)hh; lv[7]=(short)ll;
      *(short8*)((char*)&sX[0][0] + b*128 + s*16) = hv;
      *(short8*)((char*)&sX[1][0] + b*128 + s*16) = lv;
    }
    __syncthreads();
    int rb = w*16 + r16;
    #pragma unroll
    for (int kh = 0; kh < 2; kh++){
      int pa = kh*4 + q;
      int offB = rb*128 + ((pa ^ (rb & 7))*16);
      short8 xh = *(const short8*)((const char*)&sX[0][0] + offB);
      short8 xl = *(const short8*)((const char*)&sX[1][0] + offB);
      short8 hh8 = *(const short8*)((const char*)&sH[0][0] + offB);
      short8 hl8 = *(const short8*)((const char*)&sH[1][0] + offB);
      #pragma unroll
      for (int g = 0; g < 6; g++){
        int ra = g*16 + r16;
        int offA = ra*128 + ((pa ^ (ra & 7))*16);
        short8 ah = *(const short8*)((const char*)&sA[0][0] + offA);
        short8 al = *(const short8*)((const char*)&sA[1][0] + offA);
        short8 bh = (g < 3) ? xh : hh8;
        short8 bl = (g < 3) ? xl : hl8;
        acc[g] = __builtin_amdgcn_mfma_f32_16x16x32_bf16(ah, bh, acc[g], 0,0,0);
        acc[g] = __builtin_amdgcn_mfma_f32_16x16x32_bf16(ah, bl, acc[g], 0,0,0);
        acc[g] = __builtin_amdgcn_mfma_f32_16x16x32_bf16(al, bh, acc[g], 0,0,0);
      }
    }
    __syncthreads();
  }

  int b = bbase + w*16 + r16;
  #pragma unroll
  for (int reg = 0; reg < 4; reg++){
    int j = jbase + q*4 + reg;
    float gr = acc[0][reg] + acc[3][reg] + bih[j]      + bhh[j];
    float gz = acc[1][reg] + acc[4][reg] + bih[j+NH]   + bhh[j+NH];
    float in_ = acc[2][reg] + bih[j+2*NH];
    float hn_ = acc[5][reg] + bhh[j+2*NH];
    float r = 1.f/(1.f + expf(-gr));
    float z = 1.f/(1.f + expf(-gz));
    float n = tanhf(in_ + r*hn_);
    float hp = hprev[(size_t)b*NH + j];
    float val = (1.f - z)*n + z*hp;
    hnew[(size_t)b*NH + j] = val;
    unsigned short sh, sl; split2(val, sh, sl);
    nhhi[(size_t)b*NH + j] = sh;
    nhlo[(size_t)b*NH + j] = sl;
  }
}

// ---------------- MFMA logits tile + partial argmax (BK=64) ----------------
__global__ __launch_bounds__(256) void k_pred_mf(
    const unsigned short* __restrict__ Hhi, const unsigned short* __restrict__ Hlo,
    const unsigned short* __restrict__ Whi, const unsigned short* __restrict__ Wlo,
    const float* __restrict__ bp,
    float* __restrict__ pval, int* __restrict__ pidx){
  __shared__ __align__(16) unsigned short sAh[128*64];
  __shared__ __align__(16) unsigned short sAl[128*64];
  __shared__ __align__(16) unsigned short sBh[128*64];
  __shared__ __align__(16) unsigned short sBl[128*64];
  __shared__ float sval[256];
  __shared__ int   sidx[256];
  int tid = threadIdx.x, w = tid >> 6, lane = tid & 63;
  int vt = blockIdx.x, vbase = vt*128, bbase = blockIdx.y*128;
  int mhalf = w & 1, nhalf = w >> 1;
  unsigned short* mybuf = (w==0)?sAh:(w==1)?sAl:(w==2)?sBh:sBl;
  const unsigned short* gsrc = (w==0)?Whi:(w==1)?Wlo:(w==2)?Hhi:Hlo;
  int rowbase = (w < 2) ? vbase : bbase;
  int isA = (w < 2);
  int rl = lane >> 3, sl = lane & 7;
  int pq = sl ^ rl;
  float4v acc[4][4];
  #pragma unroll
  for (int mi=0;mi<4;mi++)
    #pragma unroll
    for (int ni=0;ni<4;ni++) acc[mi][ni] = (float4v){0.f,0.f,0.f,0.f};
  int q = lane >> 4, b16 = lane & 15;

  for (int k0 = 0; k0 < NH; k0 += 64){
    #pragma unroll
    for (int t = 0; t < 16; t++){
      int grow = rowbase + t*8 + rl;
      if (isA && grow > NV-1) grow = NV-1;
      const unsigned short* gp = gsrc + (size_t)grow*NH + k0 + pq*8;
      async_load16(gp, (char*)mybuf + t*1024);
    }
    __syncthreads();
    #pragma unroll
    for (int kh = 0; kh < 2; kh++){
      int pa = kh*4 + q;
      short8 ah[4], al[4], bh[4], bl[4];
      #pragma unroll
      for (int mi=0;mi<4;mi++){
        int r = mhalf*64 + mi*16 + b16;
        int off = r*128 + ((pa ^ (r & 7))*16);
        ah[mi] = *(const short8*)((const char*)sAh + off);
        al[mi] = *(const short8*)((const char*)sAl + off);
      }
      #pragma unroll
      for (int ni=0;ni<4;ni++){
        int r = nhalf*64 + ni*16 + b16;
        int off = r*128 + ((pa ^ (r & 7))*16);
        bh[ni] = *(const short8*)((const char*)sBh + off);
        bl[ni] = *(const short8*)((const char*)sBl + off);
      }
      #pragma unroll
      for (int mi=0;mi<4;mi++)
        #pragma unroll
        for (int ni=0;ni<4;ni++){
          acc[mi][ni] = __builtin_amdgcn_mfma_f32_16x16x32_bf16(ah[mi], bh[ni], acc[mi][ni], 0,0,0);
          acc[mi][ni] = __builtin_amdgcn_mfma_f32_16x16x32_bf16(ah[mi], bl[ni], acc[mi][ni], 0,0,0);
          acc[mi][ni] = __builtin_amdgcn_mfma_f32_16x16x32_bf16(al[mi], bh[ni], acc[mi][ni], 0,0,0);
        }
    }
    __syncthreads();
  }

  float bestv[4] = {-INFINITY,-INFINITY,-INFINITY,-INFINITY};
  int   besti[4] = {0x7fffffff,0x7fffffff,0x7fffffff,0x7fffffff};
  #pragma unroll
  for (int mi=0;mi<4;mi++){
    #pragma unroll
    for (int reg=0;reg<4;reg++){
      int v = vbase + mhalf*64 + mi*16 + q*4 + reg;
      if (v < NV){
        float bpv = bp[v];
        #pragma unroll
        for (int ni=0;ni<4;ni++){
          float cand = acc[mi][ni][reg] + bpv;
          if (cand > bestv[ni] || (cand == bestv[ni] && v < besti[ni])){
            bestv[ni] = cand; besti[ni] = v;
          }
        }
      }
    }
  }
  #pragma unroll
  for (int ni=0;ni<4;ni++){
    #pragma unroll
    for (int off=16; off<=32; off<<=1){
      float ov = __shfl_xor(bestv[ni], off);
      int   oi = __shfl_xor(besti[ni], off);
      if (ov > bestv[ni] || (ov == bestv[ni] && oi < besti[ni])){
        bestv[ni] = ov; besti[ni] = oi;
      }
    }
    if (lane < 16){
      sval[w*64 + ni*16 + b16] = bestv[ni];
      sidx[w*64 + ni*16 + b16] = besti[ni];
    }
  }
  __syncthreads();
  if (tid < 128){
    int nh = tid >> 6;
    int wA = nh*2, wB = nh*2 + 1;
    int slot = tid & 63;
    float vA = sval[wA*64 + slot], vB = sval[wB*64 + slot];
    int   iA = sidx[wA*64 + slot], iB = sidx[wB*64 + slot];
    bool takeB = (vB > vA) || (vB == vA && iB < iA);
    pval[vt*BATCH + bbase + tid] = takeB ? vB : vA;
    pidx[vt*BATCH + bbase + tid] = takeB ? iB : iA;
  }
}

// ---------------- final argmax -> preds last col ----------------
__global__ void k_fin(const float* __restrict__ pval, const int* __restrict__ pidx,
                      int* __restrict__ preds, int col, int nvt){
  __shared__ float rav[32*8];
  __shared__ int   rai[32*8];
  int tid = threadIdx.x;
  int bbase = blockIdx.x * 32;
  int bl = tid >> 3, l8 = tid & 7;
  float best = -INFINITY; int bidx = 0x7fffffff;
  for (int p = l8; p < nvt; p += 8){
    float v = pval[p*BATCH + bbase + bl];
    int   i = pidx[p*BATCH + bbase + bl];
    if (v > best || (v == best && i < bidx)){ best = v; bidx = i; }
  }
  rav[bl*8+l8] = best; rai[bl*8+l8] = bidx;
  __syncthreads();
  if (tid < 32){
    float bb = -INFINITY; int bi = 0x7fffffff;
    #pragma unroll
    for (int t=0;t<8;t++){
      float v = rav[tid*8+t]; int i = rai[tid*8+t];
      if (v > bb || (v == bb && i < bi)){ bb = v; bi = i; }
    }
    preds[(bbase+tid)*NT + col] = bi;
  }
}

// ================= fp32 fallback path (round-1, kept for ws safety) =================
__global__ __launch_bounds__(256) void k_h0_fb(const float* __restrict__ img,
                                            const float* __restrict__ Wc,
                                            const float* __restrict__ bc,
                                            float* __restrict__ h0){
  __shared__ float As[64*36];
  __shared__ float Bs[64*36];
  int tid = threadIdx.x;
  int tx = tid & 15, ty = tid >> 4;
  int jbase = blockIdx.x * 64;
  int bbase = blockIdx.y * 64;
  int lrow = tid >> 3;
  int lc4  = (tid & 7) << 2;
  float acc[4][4] = {};
  for (int k0 = 0; k0 < NCOND; k0 += 32){
    #pragma unroll
    for (int rr = 0; rr < 64; rr += 32){
      *(float4*)&As[(lrow+rr)*36 + lc4] =
          *(const float4*)(img + (size_t)(bbase+lrow+rr)*NCOND + k0 + lc4);
      *(float4*)&Bs[(lrow+rr)*36 + lc4] =
          *(const float4*)(Wc + (size_t)(jbase+lrow+rr)*NCOND + k0 + lc4);
    }
    __syncthreads();
    #pragma unroll
    for (int kk = 0; kk < 32; kk += 4){
      float4 a[4], w[4];
      #pragma unroll
      for (int i=0;i<4;i++) a[i] = *(float4*)&As[(ty+16*i)*36+kk];
      #pragma unroll
      for (int j=0;j<4;j++) w[j] = *(float4*)&Bs[(tx+16*j)*36+kk];
      #pragma unroll
      for (int i=0;i<4;i++)
        #pragma unroll
        for (int j=0;j<4;j++)
          acc[i][j] += a[i].x*w[j].x + a[i].y*w[j].y + a[i].z*w[j].z + a[i].w*w[j].w;
    }
    __syncthreads();
  }
  #pragma unroll
  for (int i=0;i<4;i++){
    int b = bbase + ty + 16*i;
    #pragma unroll
    for (int j=0;j<4;j++){
      int jj = jbase + tx + 16*j;
      h0[(size_t)b*NH + jj] = acc[i][j] + bc[jj];
    }
  }
}

__global__ __launch_bounds__(256) void k_pred_f32(const float* __restrict__ h,
                                              const float* __restrict__ Wp,
                                              const float* __restrict__ bp,
                                              float* __restrict__ pval,
                                              int* __restrict__ pidx){
  __shared__ float As[64*36];
  __shared__ float Bs[64*36];
  __shared__ float rv[64*16];
  __shared__ int   ri[64*16];
  int tid = threadIdx.x;
  int tx = tid & 15, ty = tid >> 4;
  int vt = blockIdx.x;
  int vbase = vt * 64;
  int bbase = blockIdx.y * 64;
  int lrow = tid >> 3;
  int lc4  = (tid & 7) << 2;
  float acc[4][4] = {};
  for (int k0 = 0; k0 < NH; k0 += 32){
    #pragma unroll
    for (int rr = 0; rr < 64; rr += 32){
      *(float4*)&As[(lrow+rr)*36 + lc4] =
          *(const float4*)(h + (size_t)(bbase+lrow+rr)*NH + k0 + lc4);
      int v = vbase + lrow + rr;
      float4 wv = make_float4(0.f,0.f,0.f,0.f);
      if (v < NV) wv = *(const float4*)(Wp + (size_t)v*NH + k0 + lc4);
      *(float4*)&Bs[(lrow+rr)*36 + lc4] = wv;
    }
    __syncthreads();
    #pragma unroll
    for (int kk = 0; kk < 32; kk += 4){
      float4 a[4], wv[4];
      #pragma unroll
      for (int i=0;i<4;i++) a[i] = *(float4*)&As[(ty+16*i)*36+kk];
      #pragma unroll
      for (int j=0;j<4;j++) wv[j] = *(float4*)&Bs[(tx+16*j)*36+kk];
      #pragma unroll
      for (int i=0;i<4;i++)
        #pragma unroll
        for (int j=0;j<4;j++)
          acc[i][j] += a[i].x*wv[j].x + a[i].y*wv[j].y + a[i].z*wv[j].z + a[i].w*wv[j].w;
    }
    __syncthreads();
  }
  #pragma unroll
  for (int i=0;i<4;i++){
    int bl = ty + 16*i;
    float best = -INFINITY; int bidx = 0;
    #pragma unroll
    for (int j=0;j<4;j++){
      int v = vbase + tx + 16*j;
      if (v < NV){
        float val = acc[i][j] + bp[v];
        if (val > best){ best = val; bidx = v; }
      }
    }
    rv[bl*16+tx] = best; ri[bl*16+tx] = bidx;
  }
  __syncthreads();
  if (tid < 64){
    float best = -INFINITY; int bidx = 0;
    #pragma unroll
    for (int t=0;t<16;t++){
      float v = rv[tid*16+t];
      if (v > best){ best = v; bidx = ri[tid*16+t]; }
    }
    pval[vt*BATCH + bbase + tid] = best;
    pidx[vt*BATCH + bbase + tid] = bidx;
  }
}

__global__ __launch_bounds__(256) void k_gru_fb(const int* __restrict__ cap,
    const float* __restrict__ pval, const int* __restrict__ pidx,
    const float* __restrict__ emb,
    const float* __restrict__ wih, const float* __restrict__ whh,
    const float* __restrict__ bih, const float* __restrict__ bhh,
    const float* __restrict__ hprev, float* __restrict__ hnew,
    int* __restrict__ preds, int use_caption, int pred_col, int nvt){
  __shared__ int   s_tok[32];
  __shared__ float rav[32*8];
  __shared__ int   rai[32*8];
  __shared__ float xs[32*36];
  __shared__ float hs[32*36];
  __shared__ float wis[3*16*36];
  __shared__ float whs[3*16*36];
  int tid = threadIdx.x;
  int tx = tid & 15, ty = tid >> 4;
  int jbase = blockIdx.x * 16;
  int bbase = blockIdx.y * 32;

  if (use_caption){
    if (tid < 32) s_tok[tid] = cap[bbase + tid];
  } else {
    int bl = tid >> 3, l8 = tid & 7;
    float best = -INFINITY; int bidx = 0x7fffffff;
    for (int p = l8; p < nvt; p += 8){
      float v = pval[p*BATCH + bbase + bl];
      int   i = pidx[p*BATCH + bbase + bl];
      if (v > best || (v == best && i < bidx)){ best = v; bidx = i; }
    }
    rav[bl*8 + l8] = best; rai[bl*8 + l8] = bidx;
    __syncthreads();
    if (tid < 32){
      float bb = -INFINITY; int bi = 0x7fffffff;
      #pragma unroll
      for (int t=0;t<8;t++){
        float v = rav[tid*8+t]; int i = rai[tid*8+t];
        if (v > bb || (v == bb && i < bi)){ bb = v; bi = i; }
      }
      s_tok[tid] = bi;
      if (blockIdx.x == 0) preds[(bbase+tid)*NT + pred_col] = bi;
    }
  }
  __syncthreads();

  float acc[2][6] = {};
  int lrow = tid >> 3;
  int lc4  = (tid & 7) << 2;
  for (int k0 = 0; k0 < NH; k0 += 32){
    int tokr = s_tok[lrow];
    *(float4*)&xs[lrow*36 + lc4] =
        *(const float4*)(emb + (size_t)tokr*NH + k0 + lc4);
    *(float4*)&hs[lrow*36 + lc4] =
        *(const float4*)(hprev + (size_t)(bbase+lrow)*NH + k0 + lc4);
    #pragma unroll
    for (int qy = tid; qy < 768; qy += 256){
      int g  = qy >> 7;
      int r  = (qy >> 3) & 15;
      int cc = (qy & 7) << 2;
      const float* wsrc = (g < 3) ? wih : whh;
      int gg = (g < 3) ? g : (g - 3);
      float* dst = (g < 3) ? wis : whs;
      *(float4*)&dst[gg*576 + r*36 + cc] =
          *(const float4*)(wsrc + (size_t)(gg*NH + jbase + r)*NH + k0 + cc);
    }
    __syncthreads();
    #pragma unroll
    for (int kk = 0; kk < 32; kk += 4){
      float4 x0 = *(float4*)&xs[ty*36+kk];
      float4 x1 = *(float4*)&xs[(ty+16)*36+kk];
      float4 h0v = *(float4*)&hs[ty*36+kk];
      float4 h1v = *(float4*)&hs[(ty+16)*36+kk];
      #pragma unroll
      for (int g=0; g<3; g++){
        float4 wi4 = *(float4*)&wis[g*576 + tx*36 + kk];
        float4 wh4 = *(float4*)&whs[g*576 + tx*36 + kk];
        acc[0][g]   += x0.x*wi4.x + x0.y*wi4.y + x0.z*wi4.z + x0.w*wi4.w;
        acc[1][g]   += x1.x*wi4.x + x1.y*wi4.y + x1.z*wi4.z + x1.w*wi4.w;
        acc[0][3+g] += h0v.x*wh4.x + h0v.y*wh4.y + h0v.z*wh4.z + h0v.w*wh4.w;
        acc[1][3+g] += h1v.x*wh4.x + h1v.y*wh4.y + h1v.z*wh4.z + h1v.w*wh4.w;
      }
    }
    __syncthreads();
  }
  int j = jbase + tx;
  float bi_r = bih[j], bi_z = bih[j+NH], bi_n = bih[j+2*NH];
  float bh_r = bhh[j], bh_z = bhh[j+NH], bh_n = bhh[j+2*NH];
  #pragma unroll
  for (int i=0;i<2;i++){
    int b = bbase + ty + 16*i;
    float r = 1.f/(1.f + expf(-((acc[i][0]+bi_r) + (acc[i][3]+bh_r))));
    float z = 1.f/(1.f + expf(-((acc[i][1]+bi_z) + (acc[i][4]+bh_z))));
    float n = tanhf((acc[i][2]+bi_n) + r*(acc[i][5]+bh_n));
    float hp = hprev[(size_t)b*NH + j];
    hnew[(size_t)b*NH + j] = (1.f - z)*n + z*hp;
  }
}

extern "C" void kernel_launch(void* const* d_in, const int* in_sizes, int n_in,
                              void* d_out, int out_size, void* d_ws, size_t ws_size,
                              hipStream_t stream){
  const int*   cap = (const int*)d_in[0];
  const float* img = (const float*)d_in[1];
  const float* emb = (const float*)d_in[2];
  const float* Wc  = (const float*)d_in[3];
  const float* bc  = (const float*)d_in[4];
  const float* wih = (const float*)d_in[5];
  const float* whh = (const float*)d_in[6];
  const float* bih = (const float*)d_in[7];
  const float* bhh = (const float*)d_in[8];
  const float* Wp  = (const float*)d_in[9];
  const float* bp  = (const float*)d_in[10];
  int* preds = (int*)d_out;

  char* p = (char*)d_ws;
  float* h0b = (float*)p;                   p += (size_t)BATCH*NH*4;
  float* h1b = (float*)p;                   p += (size_t)BATCH*NH*4;
  float* pval = (float*)p;                  p += (size_t)NVT_F32*BATCH*4;
  int*   pidx = (int*)p;                    p += (size_t)NVT_F32*BATCH*4;
  unsigned short* Hhi0 = (unsigned short*)p; p += (size_t)BATCH*NH*2;
  unsigned short* Hlo0 = (unsigned short*)p; p += (size_t)BATCH*NH*2;
  unsigned short* Hhi1 = (unsigned short*)p; p += (size_t)BATCH*NH*2;
  unsigned short* Hlo1 = (unsigned short*)p; p += (size_t)BATCH*NH*2;
  unsigned short* Whi = (unsigned short*)p;  p += (size_t)NV*NH*2;
  unsigned short* Wlo = (unsigned short*)p;  p += (size_t)NV*NH*2;
  unsigned short* W6hi = (unsigned short*)p; p += (size_t)3072*NH*2;
  unsigned short* W6lo = (unsigned short*)p; p += (size_t)3072*NH*2;
  unsigned short* Wchi = (unsigned short*)p; p += (size_t)NH*NCOND*2;
  unsigned short* Wclo = (unsigned short*)p; p += (size_t)NH*NCOND*2;
  size_t need = (size_t)(p - (char*)d_ws);

  bool use_mfma = (ws_size >= need);

  k_seed<<<1, 256, 0, stream>>>(cap, preds);
  float* hb[2] = {h0b, h1b};

  if (use_mfma){
    k_split_all<<<dim3(SPLIT_BLOCKS), 256, 0, stream>>>(Wp, wih, whh, Wc,
                                                        Whi, Wlo, W6hi, W6lo, Wchi, Wclo);
    k_h0_mf<<<dim3(NH/16, BATCH/64), 256, 0, stream>>>(img, Wchi, Wclo, bc,
                                                       h0b, Hhi0, Hlo0);
    unsigned short* Hhs[2] = {Hhi0, Hhi1};
    unsigned short* Hls[2] = {Hlo0, Hlo1};
    for (int s = 1; s <= NT-1; s++){
      int pi = (s-1)&1, ci = s&1;
      k_gru_mf<<<dim3(NH/16, BATCH/64), 256, 0, stream>>>(cap, pval, pidx, emb,
          W6hi, W6lo, Hhs[pi], Hls[pi], bih, bhh,
          hb[pi], hb[ci], Hhs[ci], Hls[ci], preds, (s==1)?1:0, s-1);
      k_pred_mf<<<dim3(NVT_MF, 2), 256, 0, stream>>>(Hhs[ci], Hls[ci], Whi, Wlo,
                                                     bp, pval, pidx);
    }
    k_fin<<<dim3(BATCH/32), 256, 0, stream>>>(pval, pidx, preds, NT-1, NVT_MF);
  } else {
    k_h0_fb<<<dim3(NH/64, BATCH/64), 256, 0, stream>>>(img, Wc, bc, h0b);
    for (int s = 1; s <= NT-1; s++){
      const float* hprev = hb[(s-1)&1];
      float* hnew = hb[s&1];
      k_gru_fb<<<dim3(NH/16, BATCH/32), 256, 0, stream>>>(cap, pval, pidx, emb, wih, whh,
                                                       bih, bhh, hprev, hnew,
                                                       preds, (s==1)?1:0, s-1, NVT_F32);
      k_pred_f32<<<dim3(NVT_F32, BATCH/64), 256, 0, stream>>>(hnew, Wp, bp, pval, pidx);
    }
    k_fin<<<dim3(BATCH/32), 256, 0, stream>>>(pval, pidx, preds, NT-1, NVT_F32);
  }
}

// Round 4
// 829.456 us; speedup vs baseline: 4.4270x; 1.4180x over previous
//
#include <hip/hip_runtime.h>
#include <math.h>

#define BATCH 256
#define NH 512
#define NCOND 1024
#define NV 32002
#define NT 15
#define NVT_F32 501   // ceil(NV/64)  (fallback fp32 path)
#define NVT_MF  251   // ceil(NV/128) (MFMA path)

// splitter section sizes in float4 units
#define SP_P  4096256   // NV*NH/4
#define SP_IH 196608    // 1536*512/4
#define SP_HH 196608
#define SP_C  131072    // 512*1024/4
#define SPLIT_W_BLOCKS 16001              // SP_P/256
#define SPLIT_S_BLOCKS 2048               // (SP_IH+SP_HH+SP_C)/256

typedef short short8 __attribute__((ext_vector_type(8)));
typedef float float4v __attribute__((ext_vector_type(4)));

__device__ __forceinline__ void async_load16(const void* g, void* l){
  __builtin_amdgcn_global_load_lds(
      (const __attribute__((address_space(1))) void*)g,
      (__attribute__((address_space(3))) void*)l, 16, 0, 0);
}

__device__ __forceinline__ void split2(float x, unsigned short& hi, unsigned short& lo){
  unsigned u = __float_as_uint(x);
  unsigned r = u + 0x7fffu + ((u >> 16) & 1u);
  hi = (unsigned short)(r >> 16);
  float fh = __uint_as_float(r & 0xffff0000u);
  float res = x - fh;
  unsigned u2 = __float_as_uint(res);
  unsigned r2 = u2 + 0x7fffu + ((u2 >> 16) & 1u);
  lo = (unsigned short)(r2 >> 16);
}

// orderable packing: larger val wins; tie -> smaller idx (numpy argmax semantics)
__device__ __forceinline__ unsigned long long pack_key(float v, int idx){
  unsigned u = __float_as_uint(v);
  u = (u & 0x80000000u) ? ~u : (u | 0x80000000u);
  return ((unsigned long long)u << 32) | (unsigned)(0x7fffffff - idx);
}
__device__ __forceinline__ int key_tok(unsigned long long k){
  return 0x7fffffff - (int)(unsigned)(k & 0xffffffffu);
}

// ---------------- seed token -> preds col 0 ----------------
__global__ void k_seed(const int* __restrict__ cap, int* __restrict__ preds){
  int b = threadIdx.x;
  preds[b*NT + 0] = cap[b];
}

// ---------------- split W_pred fp32 -> bf16 hi/lo (the big one) ----------------
__global__ __launch_bounds__(256) void k_split_w(const float* __restrict__ Wp,
    unsigned short* __restrict__ Whi, unsigned short* __restrict__ Wlo){
  size_t i = (size_t)blockIdx.x * 256 + threadIdx.x;
  float4 v = *(const float4*)(Wp + i*4);
  unsigned short h0,l0,h1,l1,h2,l2,h3,l3;
  split2(v.x,h0,l0); split2(v.y,h1,l1); split2(v.z,h2,l2); split2(v.w,h3,l3);
  ushort4 hs = {h0,h1,h2,h3};
  ushort4 ls = {l0,l1,l2,l3};
  *(ushort4*)(Whi + i*4) = hs;
  *(ushort4*)(Wlo + i*4) = ls;
}

// ---------------- split [wih;whh] + W_cond (small, runs first) ----------------
__global__ __launch_bounds__(256) void k_split_small(
    const float* __restrict__ wih, const float* __restrict__ whh,
    const float* __restrict__ Wc,
    unsigned short* __restrict__ W6hi, unsigned short* __restrict__ W6lo,
    unsigned short* __restrict__ Wchi, unsigned short* __restrict__ Wclo){
  size_t i = (size_t)blockIdx.x * 256 + threadIdx.x;
  const float* src; unsigned short *dh, *dl; size_t off;
  if (i < SP_IH){ src = wih; dh = W6hi; dl = W6lo; off = i; }
  else if (i < SP_IH + SP_HH){
    src = whh; dh = W6hi + 786432; dl = W6lo + 786432; off = i - SP_IH;
  } else { src = Wc; dh = Wchi; dl = Wclo; off = i - SP_IH - SP_HH; }
  float4 v = *(const float4*)(src + off*4);
  unsigned short h0,l0,h1,l1,h2,l2,h3,l3;
  split2(v.x,h0,l0); split2(v.y,h1,l1); split2(v.z,h2,l2); split2(v.w,h3,l3);
  ushort4 hs = {h0,h1,h2,h3};
  ushort4 ls = {l0,l1,l2,l3};
  *(ushort4*)(dh + off*4) = hs;
  *(ushort4*)(dl + off*4) = ls;
}

// ---------------- h0 = img @ W_cond^T + b_cond  (MFMA split-bf16) ----------------
__global__ __launch_bounds__(256) void k_h0_mf(
    const float* __restrict__ img,
    const unsigned short* __restrict__ Wchi, const unsigned short* __restrict__ Wclo,
    const float* __restrict__ bc,
    float* __restrict__ h0,
    unsigned short* __restrict__ hhi, unsigned short* __restrict__ hlo){
  __shared__ __align__(16) unsigned short sA[2][16*64];
  __shared__ __align__(16) unsigned short sB[2][64*64];
  int tid = threadIdx.x, w = tid >> 6, lane = tid & 63;
  int jbase = blockIdx.x * 16, bbase = blockIdx.y * 64;
  int r16 = lane & 15, q = lane >> 4;
  float4v acc = {0.f,0.f,0.f,0.f};
  for (int k0 = 0; k0 < NCOND; k0 += 64){
    { // A: 4 passes total, wave w does pass w
      int arr = w >> 1, t = w & 1;
      int a = t*8 + (lane >> 3);
      int p = (lane & 7) ^ (lane >> 3);
      const unsigned short* gs = (arr ? Wclo : Wchi) + (size_t)(jbase + a)*NCOND + k0 + p*8;
      async_load16(gs, (char*)&sA[arr][0] + t*1024);
    }
    #pragma unroll
    for (int i = 0; i < 2; i++){ // B: img fp32 -> split -> LDS
      int u = tid + 256*i;
      int b = u >> 3, s = u & 7;
      int p = s ^ (b & 7);
      const float* gp = img + (size_t)(bbase + b)*NCOND + k0 + p*8;
      float4 f0 = *(const float4*)gp, f1 = *(const float4*)(gp + 4);
      short8 hv, lv; unsigned short hh, ll;
      split2(f0.x,hh,ll); hv[0]=(short)hh; lv[0]=(short)ll;
      split2(f0.y,hh,ll); hv[1]=(short)hh; lv[1]=(short)ll;
      split2(f0.z,hh,ll); hv[2]=(short)hh; lv[2]=(short)ll;
      split2(f0.w,hh,ll); hv[3]=(short)hh; lv[3]=(short)ll;
      split2(f1.x,hh,ll); hv[4]=(short)hh; lv[4]=(short)ll;
      split2(f1.y,hh,ll); hv[5]=(short)hh; lv[5]=(short)ll;
      split2(f1.z,hh,ll); hv[6]=(short)hh; lv[6]=(short)ll;
      split2(f1.w,hh,ll); hv[7]=(short)hh; lv[7]=(short)ll;
      *(short8*)((char*)&sB[0][0] + b*128 + s*16) = hv;
      *(short8*)((char*)&sB[1][0] + b*128 + s*16) = lv;
    }
    __syncthreads();
    int rb = w*16 + r16;
    #pragma unroll
    for (int kh = 0; kh < 2; kh++){
      int pa = kh*4 + q;
      int offA = r16*128 + ((pa ^ (r16 & 7))*16);
      int offB = rb*128 + ((pa ^ (rb & 7))*16);
      short8 ah = *(const short8*)((const char*)&sA[0][0] + offA);
      short8 al = *(const short8*)((const char*)&sA[1][0] + offA);
      short8 bh = *(const short8*)((const char*)&sB[0][0] + offB);
      short8 bl = *(const short8*)((const char*)&sB[1][0] + offB);
      acc = __builtin_amdgcn_mfma_f32_16x16x32_bf16(ah, bh, acc, 0,0,0);
      acc = __builtin_amdgcn_mfma_f32_16x16x32_bf16(ah, bl, acc, 0,0,0);
      acc = __builtin_amdgcn_mfma_f32_16x16x32_bf16(al, bh, acc, 0,0,0);
    }
    __syncthreads();
  }
  int b = bbase + w*16 + r16;
  #pragma unroll
  for (int reg = 0; reg < 4; reg++){
    int j = jbase + q*4 + reg;
    float val = acc[reg] + bc[j];
    h0[(size_t)b*NH + j] = val;
    unsigned short sh, sl; split2(val, sh, sl);
    hhi[(size_t)b*NH + j] = sh;
    hlo[(size_t)b*NH + j] = sl;
  }
}

// ---------------- fused: token-from-slot -> embed/split -> GRU (MFMA) ----------------
// grid (32, 8): 16 j x 32 b per block, BK=128 (4 chunks). Waves: (b-subtile, gate-triple).
__global__ __launch_bounds__(256) void k_gru_mf(
    const int* __restrict__ cap,
    const unsigned long long* __restrict__ slot_prev,
    const float* __restrict__ emb,
    const unsigned short* __restrict__ W6hi, const unsigned short* __restrict__ W6lo,
    const unsigned short* __restrict__ Hhi, const unsigned short* __restrict__ Hlo,
    const float* __restrict__ bih, const float* __restrict__ bhh,
    const float* __restrict__ hprev, float* __restrict__ hnew,
    unsigned short* __restrict__ nhhi, unsigned short* __restrict__ nhlo,
    int* __restrict__ preds, int use_caption, int pred_col){
  __shared__ __align__(16) unsigned short sAh[96*128];
  __shared__ __align__(16) unsigned short sAl[96*128];
  __shared__ __align__(16) unsigned short sXh[32*128];
  __shared__ __align__(16) unsigned short sXl[32*128];
  __shared__ __align__(16) unsigned short sHh[32*128];
  __shared__ __align__(16) unsigned short sHl[32*128];
  __shared__ float comb[2][768];
  __shared__ int tok[32];
  int tid = threadIdx.x, w = tid >> 6, lane = tid & 63;
  int jbase = blockIdx.x * 16, bbase = blockIdx.y * 32;
  int bsub = w & 1, grp = w >> 1;
  int b16 = lane & 15, q = lane >> 4;

  if (tid < 32){
    int t;
    if (use_caption) t = cap[bbase + tid];
    else {
      t = key_tok(slot_prev[bbase + tid]);
      if (blockIdx.x == 0) preds[(bbase + tid)*NT + pred_col] = t;
    }
    tok[tid] = t;
  }
  __syncthreads();
  int tr0 = tok[tid >> 4];
  int tr1 = tok[16 + (tid >> 4)];

  float4v acc[3];
  #pragma unroll
  for (int g = 0; g < 3; g++) acc[g] = (float4v){0.f,0.f,0.f,0.f};

  for (int k0 = 0; k0 < NH; k0 += 128){
    #pragma unroll
    for (int i = 0; i < 12; i++){ // A: 48 issues, 12/wave
      int idx = w*12 + i;
      int arr = idx >= 24, t = arr ? (idx - 24) : idx;
      int row = t*4 + (lane >> 4);
      int glocal = row >> 4, jr = row & 15;
      int slot = (lane & 15) ^ (row & 15);
      const unsigned short* gs = (arr ? W6lo : W6hi)
          + (size_t)(glocal*512 + jbase + jr)*NH + k0 + slot*8;
      async_load16(gs, (char*)(arr ? sAl : sAh) + t*1024);
    }
    #pragma unroll
    for (int i = 0; i < 4; i++){ // H: 16 issues, 4/wave
      int idx = w*4 + i;
      int arr = idx >= 8, t = idx & 7;
      int row = t*4 + (lane >> 4);
      int slot = (lane & 15) ^ (row & 15);
      const unsigned short* gs = (arr ? Hlo : Hhi)
          + (size_t)(bbase + row)*NH + k0 + slot*8;
      async_load16(gs, (char*)(arr ? sHl : sHh) + t*1024);
    }
    #pragma unroll
    for (int i = 0; i < 2; i++){ // X: emb fp32 gather -> split -> LDS
      int u = tid + 256*i;
      int row = u >> 4, slot = u & 15;
      int phys = slot ^ (row & 15);
      int tr = i ? tr1 : tr0;
      const float* gp = emb + (size_t)tr*NH + k0 + slot*8;
      float4 f0 = *(const float4*)gp, f1 = *(const float4*)(gp + 4);
      short8 hv, lv; unsigned short hh, ll;
      split2(f0.x,hh,ll); hv[0]=(short)hh; lv[0]=(short)ll;
      split2(f0.y,hh,ll); hv[1]=(short)hh; lv[1]=(short)ll;
      split2(f0.z,hh,ll); hv[2]=(short)hh; lv[2]=(short)ll;
      split2(f0.w,hh,ll); hv[3]=(short)hh; lv[3]=(short)ll;
      split2(f1.x,hh,ll); hv[4]=(short)hh; lv[4]=(short)ll;
      split2(f1.y,hh,ll); hv[5]=(short)hh; lv[5]=(short)ll;
      split2(f1.z,hh,ll); hv[6]=(short)hh; lv[6]=(short)ll;
      split2(f1.w,hh,ll); hv[7]=(short)hh; lv[7]=(short)ll;
      *(short8*)((char*)sXh + row*256 + phys*16) = hv;
      *(short8*)((char*)sXl + row*256 + phys*16) = lv;
    }
    __syncthreads();
    #pragma unroll
    for (int kh = 0; kh < 4; kh++){
      int phys = (kh*4 + q) ^ b16;
      int boff = (bsub*16 + b16)*256 + phys*16;
      short8 bh = grp ? *(const short8*)((const char*)sHh + boff)
                      : *(const short8*)((const char*)sXh + boff);
      short8 bl = grp ? *(const short8*)((const char*)sHl + boff)
                      : *(const short8*)((const char*)sXl + boff);
      #pragma unroll
      for (int gi = 0; gi < 3; gi++){
        int row = (grp*3 + gi)*16 + b16;
        int aoff = row*256 + phys*16;
        short8 ah = *(const short8*)((const char*)sAh + aoff);
        short8 al = *(const short8*)((const char*)sAl + aoff);
        acc[gi] = __builtin_amdgcn_mfma_f32_16x16x32_bf16(ah, bh, acc[gi], 0,0,0);
        acc[gi] = __builtin_amdgcn_mfma_f32_16x16x32_bf16(ah, bl, acc[gi], 0,0,0);
        acc[gi] = __builtin_amdgcn_mfma_f32_16x16x32_bf16(al, bh, acc[gi], 0,0,0);
      }
    }
    __syncthreads();
  }

  if (grp == 1){ // h-gate waves hand off
    #pragma unroll
    for (int gi = 0; gi < 3; gi++)
      #pragma unroll
      for (int reg = 0; reg < 4; reg++)
        comb[bsub][gi*256 + b16*16 + q*4 + reg] = acc[gi][reg];
  }
  __syncthreads();
  if (grp == 0){
    int b = bbase + bsub*16 + b16;
    #pragma unroll
    for (int reg = 0; reg < 4; reg++){
      int jl = q*4 + reg;
      int j = jbase + jl;
      float hr = comb[bsub][0*256 + b16*16 + jl];
      float hz = comb[bsub][1*256 + b16*16 + jl];
      float hn = comb[bsub][2*256 + b16*16 + jl];
      float gr = acc[0][reg] + hr + bih[j] + bhh[j];
      float gz = acc[1][reg] + hz + bih[j+NH] + bhh[j+NH];
      float in_ = acc[2][reg] + bih[j+2*NH];
      float hn_ = hn + bhh[j+2*NH];
      float r = 1.f/(1.f + expf(-gr));
      float z = 1.f/(1.f + expf(-gz));
      float n = tanhf(in_ + r*hn_);
      float hp = hprev[(size_t)b*NH + j];
      float val = (1.f - z)*n + z*hp;
      hnew[(size_t)b*NH + j] = val;
      unsigned short sh, sl; split2(val, sh, sl);
      nhhi[(size_t)b*NH + j] = sh;
      nhlo[(size_t)b*NH + j] = sl;
    }
  }
}

// ---------------- MFMA logits tile + atomic argmax (BK=64) ----------------
__global__ __launch_bounds__(256) void k_pred_mf(
    const unsigned short* __restrict__ Hhi, const unsigned short* __restrict__ Hlo,
    const unsigned short* __restrict__ Whi, const unsigned short* __restrict__ Wlo,
    const float* __restrict__ bp,
    unsigned long long* __restrict__ slot){
  __shared__ __align__(16) unsigned short sAh[128*64];
  __shared__ __align__(16) unsigned short sAl[128*64];
  __shared__ __align__(16) unsigned short sBh[128*64];
  __shared__ __align__(16) unsigned short sBl[128*64];
  __shared__ float sval[256];
  __shared__ int   sidx[256];
  int tid = threadIdx.x, w = tid >> 6, lane = tid & 63;
  int vt = blockIdx.x, vbase = vt*128, bbase = blockIdx.y*128;
  int mhalf = w & 1, nhalf = w >> 1;
  unsigned short* mybuf = (w==0)?sAh:(w==1)?sAl:(w==2)?sBh:sBl;
  const unsigned short* gsrc = (w==0)?Whi:(w==1)?Wlo:(w==2)?Hhi:Hlo;
  int rowbase = (w < 2) ? vbase : bbase;
  int isA = (w < 2);
  int rl = lane >> 3, sl = lane & 7;
  int pq = sl ^ rl;
  float4v acc[4][4];
  #pragma unroll
  for (int mi=0;mi<4;mi++)
    #pragma unroll
    for (int ni=0;ni<4;ni++) acc[mi][ni] = (float4v){0.f,0.f,0.f,0.f};
  int q = lane >> 4, b16 = lane & 15;

  for (int k0 = 0; k0 < NH; k0 += 64){
    #pragma unroll
    for (int t = 0; t < 16; t++){
      int grow = rowbase + t*8 + rl;
      if (isA && grow > NV-1) grow = NV-1;
      const unsigned short* gp = gsrc + (size_t)grow*NH + k0 + pq*8;
      async_load16(gp, (char*)mybuf + t*1024);
    }
    __syncthreads();
    #pragma unroll
    for (int kh = 0; kh < 2; kh++){
      int pa = kh*4 + q;
      short8 ah[4], al[4], bh[4], bl[4];
      #pragma unroll
      for (int mi=0;mi<4;mi++){
        int r = mhalf*64 + mi*16 + b16;
        int off = r*128 + ((pa ^ (r & 7))*16);
        ah[mi] = *(const short8*)((const char*)sAh + off);
        al[mi] = *(const short8*)((const char*)sAl + off);
      }
      #pragma unroll
      for (int ni=0;ni<4;ni++){
        int r = nhalf*64 + ni*16 + b16;
        int off = r*128 + ((pa ^ (r & 7))*16);
        bh[ni] = *(const short8*)((const char*)sBh + off);
        bl[ni] = *(const short8*)((const char*)sBl + off);
      }
      #pragma unroll
      for (int mi=0;mi<4;mi++)
        #pragma unroll
        for (int ni=0;ni<4;ni++){
          acc[mi][ni] = __builtin_amdgcn_mfma_f32_16x16x32_bf16(ah[mi], bh[ni], acc[mi][ni], 0,0,0);
          acc[mi][ni] = __builtin_amdgcn_mfma_f32_16x16x32_bf16(ah[mi], bl[ni], acc[mi][ni], 0,0,0);
          acc[mi][ni] = __builtin_amdgcn_mfma_f32_16x16x32_bf16(al[mi], bh[ni], acc[mi][ni], 0,0,0);
        }
    }
    __syncthreads();
  }

  float bestv[4] = {-INFINITY,-INFINITY,-INFINITY,-INFINITY};
  int   besti[4] = {0x7fffffff,0x7fffffff,0x7fffffff,0x7fffffff};
  #pragma unroll
  for (int mi=0;mi<4;mi++){
    #pragma unroll
    for (int reg=0;reg<4;reg++){
      int v = vbase + mhalf*64 + mi*16 + q*4 + reg;
      if (v < NV){
        float bpv = bp[v];
        #pragma unroll
        for (int ni=0;ni<4;ni++){
          float cand = acc[mi][ni][reg] + bpv;
          if (cand > bestv[ni] || (cand == bestv[ni] && v < besti[ni])){
            bestv[ni] = cand; besti[ni] = v;
          }
        }
      }
    }
  }
  #pragma unroll
  for (int ni=0;ni<4;ni++){
    #pragma unroll
    for (int off=16; off<=32; off<<=1){
      float ov = __shfl_xor(bestv[ni], off);
      int   oi = __shfl_xor(besti[ni], off);
      if (ov > bestv[ni] || (ov == bestv[ni] && oi < besti[ni])){
        bestv[ni] = ov; besti[ni] = oi;
      }
    }
    if (lane < 16){
      sval[w*64 + ni*16 + b16] = bestv[ni];
      sidx[w*64 + ni*16 + b16] = besti[ni];
    }
  }
  __syncthreads();
  if (tid < 128){
    int nh = tid >> 6;
    int wA = nh*2, wB = nh*2 + 1;
    int slotid = tid & 63;
    float vA = sval[wA*64 + slotid], vB = sval[wB*64 + slotid];
    int   iA = sidx[wA*64 + slotid], iB = sidx[wB*64 + slotid];
    bool takeB = (vB > vA) || (vB == vA && iB < iA);
    float bv = takeB ? vB : vA;
    int   bi = takeB ? iB : iA;
    atomicMax(slot + bbase + tid, pack_key(bv, bi));
  }
}

// ---------------- final token from slot -> preds last col ----------------
__global__ void k_fin_slot(const unsigned long long* __restrict__ slot,
                           int* __restrict__ preds){
  int b = threadIdx.x;
  preds[b*NT + (NT-1)] = key_tok(slot[b]);
}

// ================= fp32 fallback path (ws safety) =================
__global__ __launch_bounds__(256) void k_h0_fb(const float* __restrict__ img,
                                            const float* __restrict__ Wc,
                                            const float* __restrict__ bc,
                                            float* __restrict__ h0){
  __shared__ float As[64*36];
  __shared__ float Bs[64*36];
  int tid = threadIdx.x;
  int tx = tid & 15, ty = tid >> 4;
  int jbase = blockIdx.x * 64;
  int bbase = blockIdx.y * 64;
  int lrow = tid >> 3;
  int lc4  = (tid & 7) << 2;
  float acc[4][4] = {};
  for (int k0 = 0; k0 < NCOND; k0 += 32){
    #pragma unroll
    for (int rr = 0; rr < 64; rr += 32){
      *(float4*)&As[(lrow+rr)*36 + lc4] =
          *(const float4*)(img + (size_t)(bbase+lrow+rr)*NCOND + k0 + lc4);
      *(float4*)&Bs[(lrow+rr)*36 + lc4] =
          *(const float4*)(Wc + (size_t)(jbase+lrow+rr)*NCOND + k0 + lc4);
    }
    __syncthreads();
    #pragma unroll
    for (int kk = 0; kk < 32; kk += 4){
      float4 a[4], w[4];
      #pragma unroll
      for (int i=0;i<4;i++) a[i] = *(float4*)&As[(ty+16*i)*36+kk];
      #pragma unroll
      for (int j=0;j<4;j++) w[j] = *(float4*)&Bs[(tx+16*j)*36+kk];
      #pragma unroll
      for (int i=0;i<4;i++)
        #pragma unroll
        for (int j=0;j<4;j++)
          acc[i][j] += a[i].x*w[j].x + a[i].y*w[j].y + a[i].z*w[j].z + a[i].w*w[j].w;
    }
    __syncthreads();
  }
  #pragma unroll
  for (int i=0;i<4;i++){
    int b = bbase + ty + 16*i;
    #pragma unroll
    for (int j=0;j<4;j++){
      int jj = jbase + tx + 16*j;
      h0[(size_t)b*NH + jj] = acc[i][j] + bc[jj];
    }
  }
}

__global__ __launch_bounds__(256) void k_pred_f32(const float* __restrict__ h,
                                              const float* __restrict__ Wp,
                                              const float* __restrict__ bp,
                                              float* __restrict__ pval,
                                              int* __restrict__ pidx){
  __shared__ float As[64*36];
  __shared__ float Bs[64*36];
  __shared__ float rv[64*16];
  __shared__ int   ri[64*16];
  int tid = threadIdx.x;
  int tx = tid & 15, ty = tid >> 4;
  int vt = blockIdx.x;
  int vbase = vt * 64;
  int bbase = blockIdx.y * 64;
  int lrow = tid >> 3;
  int lc4  = (tid & 7) << 2;
  float acc[4][4] = {};
  for (int k0 = 0; k0 < NH; k0 += 32){
    #pragma unroll
    for (int rr = 0; rr < 64; rr += 32){
      *(float4*)&As[(lrow+rr)*36 + lc4] =
          *(const float4*)(h + (size_t)(bbase+lrow+rr)*NH + k0 + lc4);
      int v = vbase + lrow + rr;
      float4 wv = make_float4(0.f,0.f,0.f,0.f);
      if (v < NV) wv = *(const float4*)(Wp + (size_t)v*NH + k0 + lc4);
      *(float4*)&Bs[(lrow+rr)*36 + lc4] = wv;
    }
    __syncthreads();
    #pragma unroll
    for (int kk = 0; kk < 32; kk += 4){
      float4 a[4], wv[4];
      #pragma unroll
      for (int i=0;i<4;i++) a[i] = *(float4*)&As[(ty+16*i)*36+kk];
      #pragma unroll
      for (int j=0;j<4;j++) wv[j] = *(float4*)&Bs[(tx+16*j)*36+kk];
      #pragma unroll
      for (int i=0;i<4;i++)
        #pragma unroll
        for (int j=0;j<4;j++)
          acc[i][j] += a[i].x*wv[j].x + a[i].y*wv[j].y + a[i].z*wv[j].z + a[i].w*wv[j].w;
    }
    __syncthreads();
  }
  #pragma unroll
  for (int i=0;i<4;i++){
    int bl = ty + 16*i;
    float best = -INFINITY; int bidx = 0;
    #pragma unroll
    for (int j=0;j<4;j++){
      int v = vbase + tx + 16*j;
      if (v < NV){
        float val = acc[i][j] + bp[v];
        if (val > best){ best = val; bidx = v; }
      }
    }
    rv[bl*16+tx] = best; ri[bl*16+tx] = bidx;
  }
  __syncthreads();
  if (tid < 64){
    float best = -INFINITY; int bidx = 0;
    #pragma unroll
    for (int t=0;t<16;t++){
      float v = rv[tid*16+t];
      if (v > best){ best = v; bidx = ri[tid*16+t]; }
    }
    pval[vt*BATCH + bbase + tid] = best;
    pidx[vt*BATCH + bbase + tid] = bidx;
  }
}

__global__ __launch_bounds__(256) void k_gru_fb(const int* __restrict__ cap,
    const float* __restrict__ pval, const int* __restrict__ pidx,
    const float* __restrict__ emb,
    const float* __restrict__ wih, const float* __restrict__ whh,
    const float* __restrict__ bih, const float* __restrict__ bhh,
    const float* __restrict__ hprev, float* __restrict__ hnew,
    int* __restrict__ preds, int use_caption, int pred_col, int nvt){
  __shared__ int   s_tok[32];
  __shared__ float rav[32*8];
  __shared__ int   rai[32*8];
  __shared__ float xs[32*36];
  __shared__ float hs[32*36];
  __shared__ float wis[3*16*36];
  __shared__ float whs[3*16*36];
  int tid = threadIdx.x;
  int tx = tid & 15, ty = tid >> 4;
  int jbase = blockIdx.x * 16;
  int bbase = blockIdx.y * 32;

  if (use_caption){
    if (tid < 32) s_tok[tid] = cap[bbase + tid];
  } else {
    int bl = tid >> 3, l8 = tid & 7;
    float best = -INFINITY; int bidx = 0x7fffffff;
    for (int p = l8; p < nvt; p += 8){
      float v = pval[p*BATCH + bbase + bl];
      int   i = pidx[p*BATCH + bbase + bl];
      if (v > best || (v == best && i < bidx)){ best = v; bidx = i; }
    }
    rav[bl*8 + l8] = best; rai[bl*8 + l8] = bidx;
    __syncthreads();
    if (tid < 32){
      float bb = -INFINITY; int bi = 0x7fffffff;
      #pragma unroll
      for (int t=0;t<8;t++){
        float v = rav[tid*8+t]; int i = rai[tid*8+t];
        if (v > bb || (v == bb && i < bi)){ bb = v; bi = i; }
      }
      s_tok[tid] = bi;
      if (blockIdx.x == 0) preds[(bbase+tid)*NT + pred_col] = bi;
    }
  }
  __syncthreads();

  float acc[2][6] = {};
  int lrow = tid >> 3;
  int lc4  = (tid & 7) << 2;
  for (int k0 = 0; k0 < NH; k0 += 32){
    int tokr = s_tok[lrow];
    *(float4*)&xs[lrow*36 + lc4] =
        *(const float4*)(emb + (size_t)tokr*NH + k0 + lc4);
    *(float4*)&hs[lrow*36 + lc4] =
        *(const float4*)(hprev + (size_t)(bbase+lrow)*NH + k0 + lc4);
    #pragma unroll
    for (int qy = tid; qy < 768; qy += 256){
      int g  = qy >> 7;
      int r  = (qy >> 3) & 15;
      int cc = (qy & 7) << 2;
      const float* wsrc = (g < 3) ? wih : whh;
      int gg = (g < 3) ? g : (g - 3);
      float* dst = (g < 3) ? wis : whs;
      *(float4*)&dst[gg*576 + r*36 + cc] =
          *(const float4*)(wsrc + (size_t)(gg*NH + jbase + r)*NH + k0 + cc);
    }
    __syncthreads();
    #pragma unroll
    for (int kk = 0; kk < 32; kk += 4){
      float4 x0 = *(float4*)&xs[ty*36+kk];
      float4 x1 = *(float4*)&xs[(ty+16)*36+kk];
      float4 h0v = *(float4*)&hs[ty*36+kk];
      float4 h1v = *(float4*)&hs[(ty+16)*36+kk];
      #pragma unroll
      for (int g=0; g<3; g++){
        float4 wi4 = *(float4*)&wis[g*576 + tx*36 + kk];
        float4 wh4 = *(float4*)&whs[g*576 + tx*36 + kk];
        acc[0][g]   += x0.x*wi4.x + x0.y*wi4.y + x0.z*wi4.z + x0.w*wi4.w;
        acc[1][g]   += x1.x*wi4.x + x1.y*wi4.y + x1.z*wi4.z + x1.w*wi4.w;
        acc[0][3+g] += h0v.x*wh4.x + h0v.y*wh4.y + h0v.z*wh4.z + h0v.w*wh4.w;
        acc[1][3+g] += h1v.x*wh4.x + h1v.y*wh4.y + h1v.z*wh4.z + h1v.w*wh4.w;
      }
    }
    __syncthreads();
  }
  int j = jbase + tx;
  float bi_r = bih[j], bi_z = bih[j+NH], bi_n = bih[j+2*NH];
  float bh_r = bhh[j], bh_z = bhh[j+NH], bh_n = bhh[j+2*NH];
  #pragma unroll
  for (int i=0;i<2;i++){
    int b = bbase + ty + 16*i;
    float r = 1.f/(1.f + expf(-((acc[i][0]+bi_r) + (acc[i][3]+bh_r))));
    float z = 1.f/(1.f + expf(-((acc[i][1]+bi_z) + (acc[i][4]+bh_z))));
    float n = tanhf((acc[i][2]+bi_n) + r*(acc[i][5]+bh_n));
    float hp = hprev[(size_t)b*NH + j];
    hnew[(size_t)b*NH + j] = (1.f - z)*n + z*hp;
  }
}

__global__ void k_fin(const float* __restrict__ pval, const int* __restrict__ pidx,
                      int* __restrict__ preds, int col, int nvt){
  __shared__ float rav[32*8];
  __shared__ int   rai[32*8];
  int tid = threadIdx.x;
  int bbase = blockIdx.x * 32;
  int bl = tid >> 3, l8 = tid & 7;
  float best = -INFINITY; int bidx = 0x7fffffff;
  for (int p = l8; p < nvt; p += 8){
    float v = pval[p*BATCH + bbase + bl];
    int   i = pidx[p*BATCH + bbase + bl];
    if (v > best || (v == best && i < bidx)){ best = v; bidx = i; }
  }
  rav[bl*8+l8] = best; rai[bl*8+l8] = bidx;
  __syncthreads();
  if (tid < 32){
    float bb = -INFINITY; int bi = 0x7fffffff;
    #pragma unroll
    for (int t=0;t<8;t++){
      float v = rav[tid*8+t]; int i = rai[tid*8+t];
      if (v > bb || (v == bb && i < bi)){ bb = v; bi = i; }
    }
    preds[(bbase+tid)*NT + col] = bi;
  }
}

extern "C" void kernel_launch(void* const* d_in, const int* in_sizes, int n_in,
                              void* d_out, int out_size, void* d_ws, size_t ws_size,
                              hipStream_t stream){
  const int*   cap = (const int*)d_in[0];
  const float* img = (const float*)d_in[1];
  const float* emb = (const float*)d_in[2];
  const float* Wc  = (const float*)d_in[3];
  const float* bc  = (const float*)d_in[4];
  const float* wih = (const float*)d_in[5];
  const float* whh = (const float*)d_in[6];
  const float* bih = (const float*)d_in[7];
  const float* bhh = (const float*)d_in[8];
  const float* Wp  = (const float*)d_in[9];
  const float* bp  = (const float*)d_in[10];
  int* preds = (int*)d_out;

  char* p = (char*)d_ws;
  float* h0b = (float*)p;                   p += (size_t)BATCH*NH*4;
  float* h1b = (float*)p;                   p += (size_t)BATCH*NH*4;
  float* pval = (float*)p;                  p += (size_t)NVT_F32*BATCH*4;
  int*   pidx = (int*)p;                    p += (size_t)NVT_F32*BATCH*4;
  unsigned short* Hhi0 = (unsigned short*)p; p += (size_t)BATCH*NH*2;
  unsigned short* Hlo0 = (unsigned short*)p; p += (size_t)BATCH*NH*2;
  unsigned short* Hhi1 = (unsigned short*)p; p += (size_t)BATCH*NH*2;
  unsigned short* Hlo1 = (unsigned short*)p; p += (size_t)BATCH*NH*2;
  unsigned short* Whi = (unsigned short*)p;  p += (size_t)NV*NH*2;
  unsigned short* Wlo = (unsigned short*)p;  p += (size_t)NV*NH*2;
  unsigned short* W6hi = (unsigned short*)p; p += (size_t)3072*NH*2;
  unsigned short* W6lo = (unsigned short*)p; p += (size_t)3072*NH*2;
  unsigned short* Wchi = (unsigned short*)p; p += (size_t)NH*NCOND*2;
  unsigned short* Wclo = (unsigned short*)p; p += (size_t)NH*NCOND*2;
  unsigned long long* slots = (unsigned long long*)p; p += (size_t)NT*BATCH*8;
  size_t need = (size_t)(p - (char*)d_ws);

  bool use_mfma = (ws_size >= need);

  k_seed<<<1, 256, 0, stream>>>(cap, preds);
  float* hb[2] = {h0b, h1b};

  if (use_mfma){
    hipMemsetAsync(slots, 0, (size_t)NT*BATCH*8, stream);
    // small split first, then h0 + gru(1) (independent of W_pred split),
    // then the big splitter whose eviction tail overlaps only pred(1).
    k_split_small<<<dim3(SPLIT_S_BLOCKS), 256, 0, stream>>>(wih, whh, Wc,
                                                            W6hi, W6lo, Wchi, Wclo);
    k_h0_mf<<<dim3(NH/16, BATCH/64), 256, 0, stream>>>(img, Wchi, Wclo, bc,
                                                       h0b, Hhi0, Hlo0);
    unsigned short* Hhs[2] = {Hhi0, Hhi1};
    unsigned short* Hls[2] = {Hlo0, Hlo1};
    k_gru_mf<<<dim3(NH/16, BATCH/32), 256, 0, stream>>>(cap, slots, emb,
        W6hi, W6lo, Hhs[0], Hls[0], bih, bhh,
        hb[0], hb[1], Hhs[1], Hls[1], preds, 1, 0);
    k_split_w<<<dim3(SPLIT_W_BLOCKS), 256, 0, stream>>>(Wp, Whi, Wlo);
    k_pred_mf<<<dim3(NVT_MF, 2), 256, 0, stream>>>(Hhs[1], Hls[1], Whi, Wlo,
                                                   bp, slots + 1*BATCH);
    for (int s = 2; s <= NT-1; s++){
      int pi = (s-1)&1, ci = s&1;
      k_gru_mf<<<dim3(NH/16, BATCH/32), 256, 0, stream>>>(cap, slots + (size_t)(s-1)*BATCH,
          emb, W6hi, W6lo, Hhs[pi], Hls[pi], bih, bhh,
          hb[pi], hb[ci], Hhs[ci], Hls[ci], preds, 0, s-1);
      k_pred_mf<<<dim3(NVT_MF, 2), 256, 0, stream>>>(Hhs[ci], Hls[ci], Whi, Wlo,
                                                     bp, slots + (size_t)s*BATCH);
    }
    k_fin_slot<<<1, 256, 0, stream>>>(slots + (size_t)(NT-1)*BATCH, preds);
  } else {
    k_h0_fb<<<dim3(NH/64, BATCH/64), 256, 0, stream>>>(img, Wc, bc, h0b);
    for (int s = 1; s <= NT-1; s++){
      const float* hprev = hb[(s-1)&1];
      float* hnew = hb[s&1];
      k_gru_fb<<<dim3(NH/16, BATCH/32), 256, 0, stream>>>(cap, pval, pidx, emb, wih, whh,
                                                       bih, bhh, hprev, hnew,
                                                       preds, (s==1)?1:0, s-1, NVT_F32);
      k_pred_f32<<<dim3(NVT_F32, BATCH/64), 256, 0, stream>>>(hnew, Wp, bp, pval, pidx);
    }
    k_fin<<<dim3(BATCH/32), 256, 0, stream>>>(pval, pidx, preds, NT-1, NVT_F32);
  }
}